// Round 4
// baseline (224.089 us; speedup 1.0000x reference)
//
#include <hip/hip_runtime.h>
#include <hip/hip_bf16.h>

#define NNODES 50000
#define NEDGES 800000
#define NFEATS 256
#define NHID 16
#define HEADS 8
#define NCLS 16
#define NEG_SLOPE 0.2f
#define TOTE (NEDGES + NNODES)
#define RSTRIDE 64      // fixed CSR row stride; P(deg+1 > 64) ~ 1e-20 for Poisson(16)
#define NBUCK 196       // buckets of 256 nodes: bucket = dst >> 8
#define NPB 256
#define BCAP 4864       // mean 4337, sigma ~66 -> +8 sigma
#define S1_EPT 16       // edges per thread in k_bin
#define BIN_BLOCKS ((TOTE + 4095) / 4096)   // 208
#define GSTRIDE 16      // gcnt padding: 1 counter per 64B line (cross-XCD atomic contention)
#define GEMM1_BLOCKS ((NNODES + 127) / 128) // 391

typedef __attribute__((ext_vector_type(8))) short short8;
typedef __attribute__((ext_vector_type(4))) float floatx4;

static __device__ __forceinline__ short f2bf(float f) {
    __hip_bfloat16 b = __float2bfloat16(f);
    return *reinterpret_cast<short*>(&b);
}

#define AS1 __attribute__((address_space(1)))
#define AS3 __attribute__((address_space(3)))

static __device__ __forceinline__ void ld_lds16(const void* g, void* l) {
#if __has_builtin(__builtin_amdgcn_global_load_lds)
    __builtin_amdgcn_global_load_lds((const AS1 void*)g, (AS3 void*)l, 16, 0, 0);
#endif
}

// ---------------- phase A: bin edges by dst>>8 (+ fused W1 pre-swizzle) --------

__global__ __launch_bounds__(256) void k_bin(const int* __restrict__ ei,
                                             int* __restrict__ gcnt, int* __restrict__ barr,
                                             const float* __restrict__ W,
                                             const float* __restrict__ a_s,
                                             const float* __restrict__ a_d,
                                             short* __restrict__ Wsw) {
    int tid = threadIdx.x;
    if (blockIdx.x >= BIN_BLOCKS) {
        int t = (blockIdx.x - BIN_BLOCKS) * 256 + tid;   // 4608 threads
        if (t >= 4608) return;
        short8 b;
        if (t < 4096) {
            int kc = t >> 9, nt = (t >> 6) & 7, lane = t & 63;
            int quad = lane >> 4, lo = lane & 15;
#pragma unroll
            for (int j = 0; j < 8; j++)
                b[j] = f2bf(W[(size_t)(kc * 32 + quad * 8 + j) * 128 + nt * 16 + lo]);
        } else {
            int t2 = t - 4096;
            int kc = t2 >> 6, lane = t2 & 63;
            int quad = lane >> 4, lo = lane & 15;
            int h = lo & 7;
            const float* av = (lo < 8) ? (a_s + h * 16) : (a_d + h * 16);
#pragma unroll
            for (int j = 0; j < 8; j++) {
                int k = kc * 32 + quad * 8 + j;
                float acc = 0.f;
#pragma unroll
                for (int c = 0; c < 16; c++) acc += W[(size_t)k * 128 + h * 16 + c] * av[c];
                b[j] = f2bf(acc);
            }
        }
        *(short8*)(Wsw + (size_t)t * 8) = b;
        return;
    }

    __shared__ int lcnt[NBUCK], lbase[NBUCK];
    if (tid < NBUCK) lcnt[tid] = 0;
    __syncthreads();
    int e0 = blockIdx.x * (256 * S1_EPT) + tid;
    int s[S1_EPT], d[S1_EPT], rk[S1_EPT];
#pragma unroll
    for (int k = 0; k < S1_EPT; k++) {
        int e = e0 + k * 256;
        bool v = e < TOTE;
        int ss = 0, dd = 0;
        if (v) {
            if (e < NEDGES) { ss = ei[e]; dd = ei[NEDGES + e]; }
            else            { ss = e - NEDGES; dd = ss; }
        }
        s[k] = ss; d[k] = dd;
        rk[k] = v ? atomicAdd(&lcnt[dd >> 8], 1) : -1;
    }
    __syncthreads();
    if (tid < NBUCK) lbase[tid] = lcnt[tid] ? atomicAdd(&gcnt[tid * GSTRIDE], lcnt[tid]) : 0;
    __syncthreads();
#pragma unroll
    for (int k = 0; k < S1_EPT; k++) {
        if (rk[k] >= 0) {
            int b = d[k] >> 8;
            int pos = lbase[b] + rk[k];
            if (pos < BCAP)
                barr[(size_t)b * BCAP + pos] = ((d[k] & 255) << 16) | s[k];
        }
    }
}

// ---------------- fused phase B: CSR build (blocks < NBUCK) + L1 GEMM ----------

__global__ __launch_bounds__(256) void k_mid(const int* __restrict__ gcnt,
                                             const int* __restrict__ barr,
                                             int* __restrict__ cnt, int* __restrict__ csr,
                                             const float* __restrict__ x,
                                             const short* __restrict__ Wsw,
                                             __hip_bfloat16* __restrict__ h1,
                                             float* __restrict__ as1, float* __restrict__ ad1) {
    __shared__ short smem[32768];   // 64 KB, shared by both paths
    int tid = threadIdx.x;

    if (blockIdx.x < NBUCK) {
        // ---- CSR path ----
        int* lcnt = (int*)smem;                         // 256 ints = 1 KB
        unsigned short* lcsr = (unsigned short*)smem + 512;  // 256*65 ushorts
        int b = blockIdx.x;
        lcnt[tid] = 0;
        __syncthreads();
        int n = min(gcnt[b * GSTRIDE], BCAP);
        int nodeBase = b << 8;
        for (int i = tid; i < n; i += 256) {
            int e = barr[(size_t)b * BCAP + i];
            int ln = e >> 16;
            int r = atomicAdd(&lcnt[ln], 1);
            if (r < RSTRIDE) lcsr[ln * 65 + r] = (unsigned short)(e & 0xFFFF);
        }
        __syncthreads();
        int node = nodeBase + tid;
        if (node < NNODES) cnt[node] = min(lcnt[tid], RSTRIDE);
        for (int i = tid; i < NPB * RSTRIDE; i += 256) {
            int ln = i >> 6;
            int nn = nodeBase + ln;
            if (nn < NNODES && (i & 63) < min(lcnt[ln], RSTRIDE))
                csr[(size_t)nodeBase * RSTRIDE + i] = (int)lcsr[ln * 65 + (i & 63)];
        }
        return;
    }

    // ---- GEMM1 path ----
    short* bsw = smem;
    int bid  = blockIdx.x - NBUCK;
    int wave = tid >> 6;
    int lane = tid & 63;
    int quad = lane >> 4;
    int lo   = lane & 15;

#if __has_builtin(__builtin_amdgcn_global_load_lds)
    {
        const char* gsrc = (const char*)Wsw + (size_t)wave * 1024 + (size_t)lane * 16;
        char* ldst = (char*)bsw + wave * 1024;
#pragma unroll
        for (int it = 0; it < 16; it++)
            ld_lds16(gsrc + it * 4096, ldst + it * 4096);
    }
#else
    {
        const uint4* g4 = (const uint4*)Wsw;
        uint4* l4 = (uint4*)bsw;
#pragma unroll
        for (int it = 0; it < 16; it++) l4[it * 256 + tid] = g4[it * 256 + tid];
    }
#endif
    short8 wafr[8];
#pragma unroll
    for (int kc = 0; kc < 8; kc++)
        wafr[kc] = *(const short8*)(Wsw + (size_t)(4096 + kc * 64 + lane) * 8);
    __syncthreads();

    int rowBase = bid * 128 + wave * 32;
    const float* xa[2];
#pragma unroll
    for (int mt = 0; mt < 2; mt++) {
        int row = rowBase + mt * 16 + lo;
        row = (row < NNODES) ? row : (NNODES - 1);
        xa[mt] = x + (size_t)row * 256 + quad * 8;
    }

    floatx4 acc[2][8], accA[2];
#pragma unroll
    for (int mt = 0; mt < 2; mt++) {
        accA[mt] = (floatx4){0.f, 0.f, 0.f, 0.f};
#pragma unroll
        for (int nt = 0; nt < 8; nt++) acc[mt][nt] = (floatx4){0.f, 0.f, 0.f, 0.f};
    }

    float4 a0[2], a1[2];
#pragma unroll
    for (int mt = 0; mt < 2; mt++) {
        a0[mt] = *(const float4*)(xa[mt]);
        a1[mt] = *(const float4*)(xa[mt] + 4);
    }

    for (int kc = 0; kc < 8; kc++) {
        float4 n0[2], n1[2];
        if (kc < 7) {
#pragma unroll
            for (int mt = 0; mt < 2; mt++) {
                n0[mt] = *(const float4*)(xa[mt] + (kc + 1) * 32);
                n1[mt] = *(const float4*)(xa[mt] + (kc + 1) * 32 + 4);
            }
        }
        short8 afr[2];
#pragma unroll
        for (int mt = 0; mt < 2; mt++) {
            union { short8 s; __hip_bfloat162 h[4]; } u;
            u.h[0] = __float22bfloat162_rn(make_float2(a0[mt].x, a0[mt].y));
            u.h[1] = __float22bfloat162_rn(make_float2(a0[mt].z, a0[mt].w));
            u.h[2] = __float22bfloat162_rn(make_float2(a1[mt].x, a1[mt].y));
            u.h[3] = __float22bfloat162_rn(make_float2(a1[mt].z, a1[mt].w));
            afr[mt] = u.s;
        }
#pragma unroll
        for (int nt = 0; nt < 8; nt++) {
            short8 bfr = *(const short8*)&bsw[((kc * 8 + nt) * 64 + lane) * 8];
            acc[0][nt] = __builtin_amdgcn_mfma_f32_16x16x32_bf16(afr[0], bfr, acc[0][nt], 0, 0, 0);
            acc[1][nt] = __builtin_amdgcn_mfma_f32_16x16x32_bf16(afr[1], bfr, acc[1][nt], 0, 0, 0);
        }
        accA[0] = __builtin_amdgcn_mfma_f32_16x16x32_bf16(afr[0], wafr[kc], accA[0], 0, 0, 0);
        accA[1] = __builtin_amdgcn_mfma_f32_16x16x32_bf16(afr[1], wafr[kc], accA[1], 0, 0, 0);
#pragma unroll
        for (int mt = 0; mt < 2; mt++) { a0[mt] = n0[mt]; a1[mt] = n1[mt]; }
    }

#pragma unroll
    for (int mt = 0; mt < 2; mt++)
#pragma unroll
        for (int nt = 0; nt < 8; nt++)
#pragma unroll
            for (int reg = 0; reg < 4; reg++) {
                int row = rowBase + mt * 16 + quad * 4 + reg;
                int col = nt * 16 + lo;
                if (row < NNODES)
                    h1[(size_t)row * 128 + col] = __float2bfloat16(acc[mt][nt][reg]);
            }
#pragma unroll
    for (int mt = 0; mt < 2; mt++)
#pragma unroll
        for (int reg = 0; reg < 4; reg++) {
            int row = rowBase + mt * 16 + quad * 4 + reg;
            if (row < NNODES) {
                float v = accA[mt][reg];
                if (lo < 8) as1[(size_t)row * 8 + lo] = v;
                else        ad1[(size_t)row * 8 + (lo - 8)] = v;
            }
        }
}

// ---------------- fused layer-1 aggregate + ELU + layer-2 GEMM + alpha2 --------
// Round-13: zero-LDS, zero-barrier fusion. After the cross-slot shfl_xor
// reduction EVERY lane holds the complete acc[0..7]+s (row distributed over
// the 16 cl-lanes, replicated over slots) -- no LDS handoff needed. The
// 128x16 GEMM runs in registers: lane (slot,cl) covers k=cl*8..cl*8+7 for
// outputs slot*4..slot*4+3 (8 float4 W2 loads, L2-hot), then a 4-step
// cl-group shfl reduce. Waves fully independent => own-degree bound restored
// (R3's __syncthreads re-coupled 4 nodes/block: hbm 3.0->2.0 TB/s, +3.4M
// LDS bank conflicts -- both eliminated here).

__global__ __launch_bounds__(256) void k_aggA(const int* __restrict__ cnt, const int* __restrict__ csr,
                                              const __hip_bfloat16* __restrict__ h1,
                                              const float* __restrict__ as1, const float* __restrict__ ad1,
                                              const float* __restrict__ b1,
                                              const float* __restrict__ W2,
                                              const float* __restrict__ a_s2,
                                              const float* __restrict__ a_d2,
                                              float* __restrict__ h2,
                                              float* __restrict__ as2, float* __restrict__ ad2) {
    int tid  = threadIdx.x;
    int node = blockIdx.x * 4 + (tid >> 6);            // 1 node / wave; grid exact
    int lane = tid & 63;
    int cl   = lane & 15;                              // channel-slice (8 ch)
    int slot = lane >> 4;                              // edge slot 0..3
    int head = cl >> 1;
    int deg  = min(cnt[node], RSTRIDE);                // wave-uniform
    float adst = ad1[node * 8 + head];
    int rowv = csr[node * RSTRIDE + lane];             // full row, one coalesced load

    float acc[8] = {0.f, 0.f, 0.f, 0.f, 0.f, 0.f, 0.f, 0.f};
    float s = 0.f;
    for (int i2 = 0; i2 < deg; i2 += 16) {             // 16 edges/trip, 4 per slot
        float p[4];
        union { short8 v; __hip_bfloat162 h[4]; } u[4];
#pragma unroll
        for (int t = 0; t < 4; t++) {
            int ii = i2 + slot + t * 4;
            int src = __shfl(rowv, ii & 63);
            p[t] = 0.f;
            u[t].v = (short8){0, 0, 0, 0, 0, 0, 0, 0};
            if (ii < deg) {
                u[t].v = *(const short8*)(h1 + (size_t)src * 128 + cl * 8);
                float e = as1[src * 8 + head] + adst;
                e = (e > 0.f) ? e : NEG_SLOPE * e;
                p[t] = __expf(e);
            }
        }
        s += (p[0] + p[1]) + (p[2] + p[3]);
#pragma unroll
        for (int t = 0; t < 4; t++)
#pragma unroll
            for (int q = 0; q < 4; q++) {
                float2 f = __bfloat1622float2(u[t].h[q]);
                acc[q * 2]     = fmaf(p[t], f.x, acc[q * 2]);
                acc[q * 2 + 1] = fmaf(p[t], f.y, acc[q * 2 + 1]);
            }
    }
    // cross-slot reduction (slots live in lane bits 4,5) -> ALL lanes complete
#pragma unroll
    for (int q = 0; q < 8; q++) {
        acc[q] += __shfl_xor(acc[q], 16);
        acc[q] += __shfl_xor(acc[q], 32);
    }
    s += __shfl_xor(s, 16);
    s += __shfl_xor(s, 32);

    // all lanes: softmax-normalize + bias + ELU for channels cl*8..cl*8+7
    float is = 1.f / s;
    float4 b1a = *(const float4*)(b1 + cl * 8);
    float4 b1b = *(const float4*)(b1 + cl * 8 + 4);
    float v[8];
    v[0] = acc[0] * is + b1a.x; v[1] = acc[1] * is + b1a.y;
    v[2] = acc[2] * is + b1a.z; v[3] = acc[3] * is + b1a.w;
    v[4] = acc[4] * is + b1b.x; v[5] = acc[5] * is + b1b.y;
    v[6] = acc[6] * is + b1b.z; v[7] = acc[7] * is + b1b.w;
#pragma unroll
    for (int q = 0; q < 8; q++) v[q] = (v[q] > 0.f) ? v[q] : (__expf(v[q]) - 1.f);

    // in-register layer-2 GEMM: partial over k=cl*8+q for outputs slot*4..+3
    float4 part = make_float4(0.f, 0.f, 0.f, 0.f);
#pragma unroll
    for (int q = 0; q < 8; q++) {
        float4 wrow = *(const float4*)(W2 + (size_t)(cl * 8 + q) * 16 + slot * 4);
        part.x = fmaf(v[q], wrow.x, part.x);
        part.y = fmaf(v[q], wrow.y, part.y);
        part.z = fmaf(v[q], wrow.z, part.z);
        part.w = fmaf(v[q], wrow.w, part.w);
    }
    // reduce over the cl-group (lane bits 0..3)
#pragma unroll
    for (int o = 1; o <= 8; o <<= 1) {
        part.x += __shfl_xor(part.x, o);
        part.y += __shfl_xor(part.y, o);
        part.z += __shfl_xor(part.z, o);
        part.w += __shfl_xor(part.w, o);
    }
    // each lane now holds h2[slot*4..slot*4+3]
    if (cl == 0) *(float4*)(h2 + (size_t)node * 16 + slot * 4) = part;

    float4 asv = *(const float4*)(a_s2 + slot * 4);
    float4 adv = *(const float4*)(a_d2 + slot * 4);
    float sv = part.x * asv.x + part.y * asv.y + part.z * asv.z + part.w * asv.w;
    float dv = part.x * adv.x + part.y * adv.y + part.z * adv.z + part.w * adv.w;
    sv += __shfl_xor(sv, 16); sv += __shfl_xor(sv, 32);
    dv += __shfl_xor(dv, 16); dv += __shfl_xor(dv, 32);
    if (lane == 0) { as2[node] = sv; ad2[node] = dv; }
}

// ---------------- layer-2 softmax-aggregate + bias ------------------------------

__global__ __launch_bounds__(256) void k_agg2(const int* __restrict__ cnt, const int* __restrict__ csr,
                                              const float* __restrict__ h2, const float* __restrict__ as2,
                                              const float* __restrict__ ad2, const float* __restrict__ b2,
                                              float* __restrict__ out) {
    int node = blockIdx.x * 4 + (threadIdx.x >> 6);
    int lane = threadIdx.x & 63;
    int c4   = lane & 3;                               // channel quarter (4 floats)
    int slot = lane >> 2;                              // edge slot 0..15
    int deg  = min(cnt[node], RSTRIDE);                // wave-uniform
    float adst = ad2[node];
    int rowv = csr[node * RSTRIDE + lane];

    float4 acc = make_float4(0.f, 0.f, 0.f, 0.f);
    float s = 0.f;
    for (int i2 = 0; i2 < deg; i2 += 32) {             // 32 edges/trip, 2 per slot
        int ia = i2 + slot;
        int ib = ia + 16;
        int sa = __shfl(rowv, ia & 63);
        int sb = __shfl(rowv, ib & 63);
        float p0 = 0.f, p1 = 0.f;
        float4 r0 = make_float4(0.f, 0.f, 0.f, 0.f);
        float4 r1 = make_float4(0.f, 0.f, 0.f, 0.f);
        if (ia < deg) {
            r0 = *(const float4*)(h2 + (size_t)sa * 16 + c4 * 4);
            float e = as2[sa] + adst;
            e = (e > 0.f) ? e : NEG_SLOPE * e;
            p0 = __expf(e);
        }
        if (ib < deg) {
            r1 = *(const float4*)(h2 + (size_t)sb * 16 + c4 * 4);
            float e = as2[sb] + adst;
            e = (e > 0.f) ? e : NEG_SLOPE * e;
            p1 = __expf(e);
        }
        s += p0 + p1;
        acc.x = fmaf(p0, r0.x, fmaf(p1, r1.x, acc.x));
        acc.y = fmaf(p0, r0.y, fmaf(p1, r1.y, acc.y));
        acc.z = fmaf(p0, r0.z, fmaf(p1, r1.z, acc.z));
        acc.w = fmaf(p0, r0.w, fmaf(p1, r1.w, acc.w));
    }
#pragma unroll
    for (int o = 4; o <= 32; o <<= 1) {                // reduce over 16 slots
        acc.x += __shfl_xor(acc.x, o);
        acc.y += __shfl_xor(acc.y, o);
        acc.z += __shfl_xor(acc.z, o);
        acc.w += __shfl_xor(acc.w, o);
        s += __shfl_xor(s, o);
    }
    if (slot == 0) {
        float is = 1.f / s;
        float4 o4;
        o4.x = acc.x * is + b2[c4 * 4 + 0];
        o4.y = acc.y * is + b2[c4 * 4 + 1];
        o4.z = acc.z * is + b2[c4 * 4 + 2];
        o4.w = acc.w * is + b2[c4 * 4 + 3];
        *(float4*)(out + (size_t)node * 16 + c4 * 4) = o4;
    }
}

// ---------------- launch ----------------

extern "C" void kernel_launch(void* const* d_in, const int* in_sizes, int n_in,
                              void* d_out, int out_size, void* d_ws, size_t ws_size,
                              hipStream_t stream) {
    const float* x    = (const float*)d_in[0];
    const int*   ei   = (const int*)d_in[1];
    const float* W1   = (const float*)d_in[2];
    const float* a_s1 = (const float*)d_in[3];
    const float* a_d1 = (const float*)d_in[4];
    const float* b1   = (const float*)d_in[5];
    const float* W2   = (const float*)d_in[6];
    const float* a_s2 = (const float*)d_in[7];
    const float* a_d2 = (const float*)d_in[8];
    const float* b2   = (const float*)d_in[9];
    float* out = (float*)d_out;

    char* p = (char*)d_ws;
    auto alloc = [&](size_t bytes) -> char* {
        char* q = p;
        p += (bytes + 255) & ~(size_t)255;
        return q;
    };
    int*  gcnt = (int*)alloc((size_t)NBUCK * GSTRIDE * 4);        // 12.5 KB, padded
    int*  barr = (int*)alloc((size_t)NBUCK * BCAP * 4);           // 3.8 MB, dead after k_mid
    int*  cnt  = (int*)alloc((size_t)NNODES * 4);
    int*  csr  = (int*)alloc((size_t)NNODES * RSTRIDE * 4);       // 12.8 MB
    short* Wsw = (short*)alloc((size_t)36864 * 2);                // 8 B-tiles + Wa tile
    __hip_bfloat16* h1 = (__hip_bfloat16*)alloc((size_t)NNODES * 128 * 2);
    float* as1 = (float*)alloc((size_t)NNODES * 8 * 4);
    float* ad1 = (float*)alloc((size_t)NNODES * 8 * 4);
    float* h2  = (float*)alloc((size_t)NNODES * 16 * 4);          // own region: as1/ad1 are
                                                                  // live concurrently in k_aggA
    // aliases (regions dead by the time these are written):
    float* as2 = (float*)barr;           // over barr (dead after k_mid)
    float* ad2 = (float*)barr + NNODES;

    hipMemsetAsync(gcnt, 0, (size_t)NBUCK * GSTRIDE * 4, stream);
    hipLaunchKernelGGL(k_bin,   dim3(BIN_BLOCKS + 18), dim3(256), 0, stream,
                       ei, gcnt, barr, W1, a_s1, a_d1, Wsw);
    hipLaunchKernelGGL(k_mid,   dim3(NBUCK + GEMM1_BLOCKS), dim3(256), 0, stream,
                       gcnt, barr, cnt, csr, x, Wsw, h1, as1, ad1);
    hipLaunchKernelGGL(k_aggA,  dim3(NNODES / 4), dim3(256), 0, stream,
                       cnt, csr, h1, as1, ad1, b1, W2, a_s2, a_d2, h2, as2, ad2);
    hipLaunchKernelGGL(k_agg2,  dim3(NNODES / 4), dim3(256), 0, stream, cnt, csr, h2, as2, ad2, b2, out);
}

// Round 5
// 222.123 us; speedup vs baseline: 1.0089x; 1.0089x over previous
//
#include <hip/hip_runtime.h>
#include <hip/hip_bf16.h>

#define NNODES 50000
#define NEDGES 800000
#define NFEATS 256
#define NHID 16
#define HEADS 8
#define NCLS 16
#define NEG_SLOPE 0.2f
#define TOTE (NEDGES + NNODES)
#define RSTRIDE 64      // fixed CSR row stride; P(deg+1 > 64) ~ 1e-20 for Poisson(16)
#define NBUCK 196       // buckets of 256 nodes: bucket = dst >> 8
#define NPB 256
#define BCAP 4864       // mean 4337, sigma ~66 -> +8 sigma
#define S1_EPT 16       // edges per thread in k_bin
#define BIN_BLOCKS ((TOTE + 4095) / 4096)   // 208
#define GSTRIDE 16      // gcnt padding: 1 counter per 64B line (cross-XCD atomic contention)
#define GEMM1_BLOCKS ((NNODES + 127) / 128) // 391

typedef __attribute__((ext_vector_type(8))) short short8;
typedef __attribute__((ext_vector_type(4))) float floatx4;

static __device__ __forceinline__ short f2bf(float f) {
    __hip_bfloat16 b = __float2bfloat16(f);
    return *reinterpret_cast<short*>(&b);
}

#define AS1 __attribute__((address_space(1)))
#define AS3 __attribute__((address_space(3)))

static __device__ __forceinline__ void ld_lds16(const void* g, void* l) {
#if __has_builtin(__builtin_amdgcn_global_load_lds)
    __builtin_amdgcn_global_load_lds((const AS1 void*)g, (AS3 void*)l, 16, 0, 0);
#endif
}

// ---------------- phase A: bin edges by dst>>8 (+ fused W1 pre-swizzle) --------

__global__ __launch_bounds__(256) void k_bin(const int* __restrict__ ei,
                                             int* __restrict__ gcnt, int* __restrict__ barr,
                                             const float* __restrict__ W,
                                             const float* __restrict__ a_s,
                                             const float* __restrict__ a_d,
                                             short* __restrict__ Wsw) {
    int tid = threadIdx.x;
    if (blockIdx.x >= BIN_BLOCKS) {
        int t = (blockIdx.x - BIN_BLOCKS) * 256 + tid;   // 4608 threads
        if (t >= 4608) return;
        short8 b;
        if (t < 4096) {
            int kc = t >> 9, nt = (t >> 6) & 7, lane = t & 63;
            int quad = lane >> 4, lo = lane & 15;
#pragma unroll
            for (int j = 0; j < 8; j++)
                b[j] = f2bf(W[(size_t)(kc * 32 + quad * 8 + j) * 128 + nt * 16 + lo]);
        } else {
            int t2 = t - 4096;
            int kc = t2 >> 6, lane = t2 & 63;
            int quad = lane >> 4, lo = lane & 15;
            int h = lo & 7;
            const float* av = (lo < 8) ? (a_s + h * 16) : (a_d + h * 16);
#pragma unroll
            for (int j = 0; j < 8; j++) {
                int k = kc * 32 + quad * 8 + j;
                float acc = 0.f;
#pragma unroll
                for (int c = 0; c < 16; c++) acc += W[(size_t)k * 128 + h * 16 + c] * av[c];
                b[j] = f2bf(acc);
            }
        }
        *(short8*)(Wsw + (size_t)t * 8) = b;
        return;
    }

    __shared__ int lcnt[NBUCK], lbase[NBUCK];
    if (tid < NBUCK) lcnt[tid] = 0;
    __syncthreads();
    int e0 = blockIdx.x * (256 * S1_EPT) + tid;
    int s[S1_EPT], d[S1_EPT], rk[S1_EPT];
#pragma unroll
    for (int k = 0; k < S1_EPT; k++) {
        int e = e0 + k * 256;
        bool v = e < TOTE;
        int ss = 0, dd = 0;
        if (v) {
            if (e < NEDGES) { ss = ei[e]; dd = ei[NEDGES + e]; }
            else            { ss = e - NEDGES; dd = ss; }
        }
        s[k] = ss; d[k] = dd;
        rk[k] = v ? atomicAdd(&lcnt[dd >> 8], 1) : -1;
    }
    __syncthreads();
    if (tid < NBUCK) lbase[tid] = lcnt[tid] ? atomicAdd(&gcnt[tid * GSTRIDE], lcnt[tid]) : 0;
    __syncthreads();
#pragma unroll
    for (int k = 0; k < S1_EPT; k++) {
        if (rk[k] >= 0) {
            int b = d[k] >> 8;
            int pos = lbase[b] + rk[k];
            if (pos < BCAP)
                barr[(size_t)b * BCAP + pos] = ((d[k] & 255) << 16) | s[k];
        }
    }
}

// ---------------- fused phase B: CSR build (blocks < NBUCK) + L1 GEMM ----------

__global__ __launch_bounds__(256) void k_mid(const int* __restrict__ gcnt,
                                             const int* __restrict__ barr,
                                             int* __restrict__ cnt, int* __restrict__ csr,
                                             const float* __restrict__ x,
                                             const short* __restrict__ Wsw,
                                             __hip_bfloat16* __restrict__ h1,
                                             float* __restrict__ as1, float* __restrict__ ad1) {
    __shared__ short smem[32768];   // 64 KB, shared by both paths
    int tid = threadIdx.x;

    if (blockIdx.x < NBUCK) {
        // ---- CSR path ----
        int* lcnt = (int*)smem;                         // 256 ints = 1 KB
        unsigned short* lcsr = (unsigned short*)smem + 512;  // 256*65 ushorts
        int b = blockIdx.x;
        lcnt[tid] = 0;
        __syncthreads();
        int n = min(gcnt[b * GSTRIDE], BCAP);
        int nodeBase = b << 8;
        for (int i = tid; i < n; i += 256) {
            int e = barr[(size_t)b * BCAP + i];
            int ln = e >> 16;
            int r = atomicAdd(&lcnt[ln], 1);
            if (r < RSTRIDE) lcsr[ln * 65 + r] = (unsigned short)(e & 0xFFFF);
        }
        __syncthreads();
        int node = nodeBase + tid;
        if (node < NNODES) cnt[node] = min(lcnt[tid], RSTRIDE);
        for (int i = tid; i < NPB * RSTRIDE; i += 256) {
            int ln = i >> 6;
            int nn = nodeBase + ln;
            if (nn < NNODES && (i & 63) < min(lcnt[ln], RSTRIDE))
                csr[(size_t)nodeBase * RSTRIDE + i] = (int)lcsr[ln * 65 + (i & 63)];
        }
        return;
    }

    // ---- GEMM1 path ----
    short* bsw = smem;
    int bid  = blockIdx.x - NBUCK;
    int wave = tid >> 6;
    int lane = tid & 63;
    int quad = lane >> 4;
    int lo   = lane & 15;

#if __has_builtin(__builtin_amdgcn_global_load_lds)
    {
        const char* gsrc = (const char*)Wsw + (size_t)wave * 1024 + (size_t)lane * 16;
        char* ldst = (char*)bsw + wave * 1024;
#pragma unroll
        for (int it = 0; it < 16; it++)
            ld_lds16(gsrc + it * 4096, ldst + it * 4096);
    }
#else
    {
        const uint4* g4 = (const uint4*)Wsw;
        uint4* l4 = (uint4*)bsw;
#pragma unroll
        for (int it = 0; it < 16; it++) l4[it * 256 + tid] = g4[it * 256 + tid];
    }
#endif
    short8 wafr[8];
#pragma unroll
    for (int kc = 0; kc < 8; kc++)
        wafr[kc] = *(const short8*)(Wsw + (size_t)(4096 + kc * 64 + lane) * 8);
    __syncthreads();

    int rowBase = bid * 128 + wave * 32;
    const float* xa[2];
#pragma unroll
    for (int mt = 0; mt < 2; mt++) {
        int row = rowBase + mt * 16 + lo;
        row = (row < NNODES) ? row : (NNODES - 1);
        xa[mt] = x + (size_t)row * 256 + quad * 8;
    }

    floatx4 acc[2][8], accA[2];
#pragma unroll
    for (int mt = 0; mt < 2; mt++) {
        accA[mt] = (floatx4){0.f, 0.f, 0.f, 0.f};
#pragma unroll
        for (int nt = 0; nt < 8; nt++) acc[mt][nt] = (floatx4){0.f, 0.f, 0.f, 0.f};
    }

    float4 a0[2], a1[2];
#pragma unroll
    for (int mt = 0; mt < 2; mt++) {
        a0[mt] = *(const float4*)(xa[mt]);
        a1[mt] = *(const float4*)(xa[mt] + 4);
    }

    for (int kc = 0; kc < 8; kc++) {
        float4 n0[2], n1[2];
        if (kc < 7) {
#pragma unroll
            for (int mt = 0; mt < 2; mt++) {
                n0[mt] = *(const float4*)(xa[mt] + (kc + 1) * 32);
                n1[mt] = *(const float4*)(xa[mt] + (kc + 1) * 32 + 4);
            }
        }
        short8 afr[2];
#pragma unroll
        for (int mt = 0; mt < 2; mt++) {
            union { short8 s; __hip_bfloat162 h[4]; } u;
            u.h[0] = __float22bfloat162_rn(make_float2(a0[mt].x, a0[mt].y));
            u.h[1] = __float22bfloat162_rn(make_float2(a0[mt].z, a0[mt].w));
            u.h[2] = __float22bfloat162_rn(make_float2(a1[mt].x, a1[mt].y));
            u.h[3] = __float22bfloat162_rn(make_float2(a1[mt].z, a1[mt].w));
            afr[mt] = u.s;
        }
#pragma unroll
        for (int nt = 0; nt < 8; nt++) {
            short8 bfr = *(const short8*)&bsw[((kc * 8 + nt) * 64 + lane) * 8];
            acc[0][nt] = __builtin_amdgcn_mfma_f32_16x16x32_bf16(afr[0], bfr, acc[0][nt], 0, 0, 0);
            acc[1][nt] = __builtin_amdgcn_mfma_f32_16x16x32_bf16(afr[1], bfr, acc[1][nt], 0, 0, 0);
        }
        accA[0] = __builtin_amdgcn_mfma_f32_16x16x32_bf16(afr[0], wafr[kc], accA[0], 0, 0, 0);
        accA[1] = __builtin_amdgcn_mfma_f32_16x16x32_bf16(afr[1], wafr[kc], accA[1], 0, 0, 0);
#pragma unroll
        for (int mt = 0; mt < 2; mt++) { a0[mt] = n0[mt]; a1[mt] = n1[mt]; }
    }

#pragma unroll
    for (int mt = 0; mt < 2; mt++)
#pragma unroll
        for (int nt = 0; nt < 8; nt++)
#pragma unroll
            for (int reg = 0; reg < 4; reg++) {
                int row = rowBase + mt * 16 + quad * 4 + reg;
                int col = nt * 16 + lo;
                if (row < NNODES)
                    h1[(size_t)row * 128 + col] = __float2bfloat16(acc[mt][nt][reg]);
            }
#pragma unroll
    for (int mt = 0; mt < 2; mt++)
#pragma unroll
        for (int reg = 0; reg < 4; reg++) {
            int row = rowBase + mt * 16 + quad * 4 + reg;
            if (row < NNODES) {
                float v = accA[mt][reg];
                if (lo < 8) as1[(size_t)row * 8 + lo] = v;
                else        ad1[(size_t)row * 8 + (lo - 8)] = v;
            }
        }
}

// ---------------- fused layer-1 aggregate + ELU + layer-2 GEMM + alpha2 --------
// Round-14: R13 structure (zero-LDS, zero-barrier in-register fusion) + two
// fixes for the R13 regression (77us, hbm 1.55 TB/s):
//  (a) asm memory fence after the gather loop: the epilogue's W2/b1/a2 loads
//      are loop-invariant; the compiler hoisted them above the loop, and the
//      ~48 VGPRs of invariant live range broke the 4-deep gather pipeline
//      (MLP 4 -> ~2 == the observed ~2x BW loss).
//  (b) __launch_bounds__(256,6): VGPR cap ~85 (was default -> 32), room for
//      the loop's u[4]+acc[8] AND some epilogue state without serializing;
//      6 waves/EU preserves the measured 75% occupancy.

__global__ __launch_bounds__(256, 6) void k_aggA(const int* __restrict__ cnt, const int* __restrict__ csr,
                                              const __hip_bfloat16* __restrict__ h1,
                                              const float* __restrict__ as1, const float* __restrict__ ad1,
                                              const float* __restrict__ b1,
                                              const float* __restrict__ W2,
                                              const float* __restrict__ a_s2,
                                              const float* __restrict__ a_d2,
                                              float* __restrict__ h2,
                                              float* __restrict__ as2, float* __restrict__ ad2) {
    int tid  = threadIdx.x;
    int node = blockIdx.x * 4 + (tid >> 6);            // 1 node / wave; grid exact
    int lane = tid & 63;
    int cl   = lane & 15;                              // channel-slice (8 ch)
    int slot = lane >> 4;                              // edge slot 0..3
    int head = cl >> 1;
    int deg  = min(cnt[node], RSTRIDE);                // wave-uniform
    float adst = ad1[node * 8 + head];
    int rowv = csr[node * RSTRIDE + lane];             // full row, one coalesced load

    float acc[8] = {0.f, 0.f, 0.f, 0.f, 0.f, 0.f, 0.f, 0.f};
    float s = 0.f;
    for (int i2 = 0; i2 < deg; i2 += 16) {             // 16 edges/trip, 4 per slot
        float p[4];
        union { short8 v; __hip_bfloat162 h[4]; } u[4];
#pragma unroll
        for (int t = 0; t < 4; t++) {
            int ii = i2 + slot + t * 4;
            int src = __shfl(rowv, ii & 63);
            p[t] = 0.f;
            u[t].v = (short8){0, 0, 0, 0, 0, 0, 0, 0};
            if (ii < deg) {
                u[t].v = *(const short8*)(h1 + (size_t)src * 128 + cl * 8);
                float e = as1[src * 8 + head] + adst;
                e = (e > 0.f) ? e : NEG_SLOPE * e;
                p[t] = __expf(e);
            }
        }
        s += (p[0] + p[1]) + (p[2] + p[3]);
#pragma unroll
        for (int t = 0; t < 4; t++)
#pragma unroll
            for (int q = 0; q < 4; q++) {
                float2 f = __bfloat1622float2(u[t].h[q]);
                acc[q * 2]     = fmaf(p[t], f.x, acc[q * 2]);
                acc[q * 2 + 1] = fmaf(p[t], f.y, acc[q * 2 + 1]);
            }
    }
    // fence: forbid hoisting the (loop-invariant) epilogue loads above the loop
    asm volatile("" ::: "memory");

    // cross-slot reduction (slots live in lane bits 4,5) -> ALL lanes complete
#pragma unroll
    for (int q = 0; q < 8; q++) {
        acc[q] += __shfl_xor(acc[q], 16);
        acc[q] += __shfl_xor(acc[q], 32);
    }
    s += __shfl_xor(s, 16);
    s += __shfl_xor(s, 32);

    // all lanes: softmax-normalize + bias + ELU for channels cl*8..cl*8+7
    float is = 1.f / s;
    float4 b1a = *(const float4*)(b1 + cl * 8);
    float4 b1b = *(const float4*)(b1 + cl * 8 + 4);
    float v[8];
    v[0] = acc[0] * is + b1a.x; v[1] = acc[1] * is + b1a.y;
    v[2] = acc[2] * is + b1a.z; v[3] = acc[3] * is + b1a.w;
    v[4] = acc[4] * is + b1b.x; v[5] = acc[5] * is + b1b.y;
    v[6] = acc[6] * is + b1b.z; v[7] = acc[7] * is + b1b.w;
#pragma unroll
    for (int q = 0; q < 8; q++) v[q] = (v[q] > 0.f) ? v[q] : (__expf(v[q]) - 1.f);

    // in-register layer-2 GEMM: partial over k=cl*8+q for outputs slot*4..+3
    float4 part = make_float4(0.f, 0.f, 0.f, 0.f);
#pragma unroll
    for (int q = 0; q < 8; q++) {
        float4 wrow = *(const float4*)(W2 + (size_t)(cl * 8 + q) * 16 + slot * 4);
        part.x = fmaf(v[q], wrow.x, part.x);
        part.y = fmaf(v[q], wrow.y, part.y);
        part.z = fmaf(v[q], wrow.z, part.z);
        part.w = fmaf(v[q], wrow.w, part.w);
    }
    // reduce over the cl-group (lane bits 0..3)
#pragma unroll
    for (int o = 1; o <= 8; o <<= 1) {
        part.x += __shfl_xor(part.x, o);
        part.y += __shfl_xor(part.y, o);
        part.z += __shfl_xor(part.z, o);
        part.w += __shfl_xor(part.w, o);
    }
    // each lane now holds h2[slot*4..slot*4+3]
    if (cl == 0) *(float4*)(h2 + (size_t)node * 16 + slot * 4) = part;

    float4 asv = *(const float4*)(a_s2 + slot * 4);
    float4 adv = *(const float4*)(a_d2 + slot * 4);
    float sv = part.x * asv.x + part.y * asv.y + part.z * asv.z + part.w * asv.w;
    float dv = part.x * adv.x + part.y * adv.y + part.z * adv.z + part.w * adv.w;
    sv += __shfl_xor(sv, 16); sv += __shfl_xor(sv, 32);
    dv += __shfl_xor(dv, 16); dv += __shfl_xor(dv, 32);
    if (lane == 0) { as2[node] = sv; ad2[node] = dv; }
}

// ---------------- layer-2 softmax-aggregate + bias ------------------------------

__global__ __launch_bounds__(256) void k_agg2(const int* __restrict__ cnt, const int* __restrict__ csr,
                                              const float* __restrict__ h2, const float* __restrict__ as2,
                                              const float* __restrict__ ad2, const float* __restrict__ b2,
                                              float* __restrict__ out) {
    int node = blockIdx.x * 4 + (threadIdx.x >> 6);
    int lane = threadIdx.x & 63;
    int c4   = lane & 3;                               // channel quarter (4 floats)
    int slot = lane >> 2;                              // edge slot 0..15
    int deg  = min(cnt[node], RSTRIDE);                // wave-uniform
    float adst = ad2[node];
    int rowv = csr[node * RSTRIDE + lane];

    float4 acc = make_float4(0.f, 0.f, 0.f, 0.f);
    float s = 0.f;
    for (int i2 = 0; i2 < deg; i2 += 32) {             // 32 edges/trip, 2 per slot
        int ia = i2 + slot;
        int ib = ia + 16;
        int sa = __shfl(rowv, ia & 63);
        int sb = __shfl(rowv, ib & 63);
        float p0 = 0.f, p1 = 0.f;
        float4 r0 = make_float4(0.f, 0.f, 0.f, 0.f);
        float4 r1 = make_float4(0.f, 0.f, 0.f, 0.f);
        if (ia < deg) {
            r0 = *(const float4*)(h2 + (size_t)sa * 16 + c4 * 4);
            float e = as2[sa] + adst;
            e = (e > 0.f) ? e : NEG_SLOPE * e;
            p0 = __expf(e);
        }
        if (ib < deg) {
            r1 = *(const float4*)(h2 + (size_t)sb * 16 + c4 * 4);
            float e = as2[sb] + adst;
            e = (e > 0.f) ? e : NEG_SLOPE * e;
            p1 = __expf(e);
        }
        s += p0 + p1;
        acc.x = fmaf(p0, r0.x, fmaf(p1, r1.x, acc.x));
        acc.y = fmaf(p0, r0.y, fmaf(p1, r1.y, acc.y));
        acc.z = fmaf(p0, r0.z, fmaf(p1, r1.z, acc.z));
        acc.w = fmaf(p0, r0.w, fmaf(p1, r1.w, acc.w));
    }
#pragma unroll
    for (int o = 4; o <= 32; o <<= 1) {                // reduce over 16 slots
        acc.x += __shfl_xor(acc.x, o);
        acc.y += __shfl_xor(acc.y, o);
        acc.z += __shfl_xor(acc.z, o);
        acc.w += __shfl_xor(acc.w, o);
        s += __shfl_xor(s, o);
    }
    if (slot == 0) {
        float is = 1.f / s;
        float4 o4;
        o4.x = acc.x * is + b2[c4 * 4 + 0];
        o4.y = acc.y * is + b2[c4 * 4 + 1];
        o4.z = acc.z * is + b2[c4 * 4 + 2];
        o4.w = acc.w * is + b2[c4 * 4 + 3];
        *(float4*)(out + (size_t)node * 16 + c4 * 4) = o4;
    }
}

// ---------------- launch ----------------

extern "C" void kernel_launch(void* const* d_in, const int* in_sizes, int n_in,
                              void* d_out, int out_size, void* d_ws, size_t ws_size,
                              hipStream_t stream) {
    const float* x    = (const float*)d_in[0];
    const int*   ei   = (const int*)d_in[1];
    const float* W1   = (const float*)d_in[2];
    const float* a_s1 = (const float*)d_in[3];
    const float* a_d1 = (const float*)d_in[4];
    const float* b1   = (const float*)d_in[5];
    const float* W2   = (const float*)d_in[6];
    const float* a_s2 = (const float*)d_in[7];
    const float* a_d2 = (const float*)d_in[8];
    const float* b2   = (const float*)d_in[9];
    float* out = (float*)d_out;

    char* p = (char*)d_ws;
    auto alloc = [&](size_t bytes) -> char* {
        char* q = p;
        p += (bytes + 255) & ~(size_t)255;
        return q;
    };
    int*  gcnt = (int*)alloc((size_t)NBUCK * GSTRIDE * 4);        // 12.5 KB, padded
    int*  barr = (int*)alloc((size_t)NBUCK * BCAP * 4);           // 3.8 MB, dead after k_mid
    int*  cnt  = (int*)alloc((size_t)NNODES * 4);
    int*  csr  = (int*)alloc((size_t)NNODES * RSTRIDE * 4);       // 12.8 MB
    short* Wsw = (short*)alloc((size_t)36864 * 2);                // 8 B-tiles + Wa tile
    __hip_bfloat16* h1 = (__hip_bfloat16*)alloc((size_t)NNODES * 128 * 2);
    float* as1 = (float*)alloc((size_t)NNODES * 8 * 4);
    float* ad1 = (float*)alloc((size_t)NNODES * 8 * 4);
    float* h2  = (float*)alloc((size_t)NNODES * 16 * 4);          // own region: as1/ad1 are
                                                                  // live concurrently in k_aggA
    // aliases (regions dead by the time these are written):
    float* as2 = (float*)barr;           // over barr (dead after k_mid)
    float* ad2 = (float*)barr + NNODES;

    hipMemsetAsync(gcnt, 0, (size_t)NBUCK * GSTRIDE * 4, stream);
    hipLaunchKernelGGL(k_bin,   dim3(BIN_BLOCKS + 18), dim3(256), 0, stream,
                       ei, gcnt, barr, W1, a_s1, a_d1, Wsw);
    hipLaunchKernelGGL(k_mid,   dim3(NBUCK + GEMM1_BLOCKS), dim3(256), 0, stream,
                       gcnt, barr, cnt, csr, x, Wsw, h1, as1, ad1);
    hipLaunchKernelGGL(k_aggA,  dim3(NNODES / 4), dim3(256), 0, stream,
                       cnt, csr, h1, as1, ad1, b1, W2, a_s2, a_d2, h2, as2, ad2);
    hipLaunchKernelGGL(k_agg2,  dim3(NNODES / 4), dim3(256), 0, stream, cnt, csr, h2, as2, ad2, b2, out);
}

// Round 6
// 210.732 us; speedup vs baseline: 1.0634x; 1.0541x over previous
//
#include <hip/hip_runtime.h>
#include <hip/hip_bf16.h>

#define NNODES 50000
#define NEDGES 800000
#define NFEATS 256
#define NHID 16
#define HEADS 8
#define NCLS 16
#define NEG_SLOPE 0.2f
#define TOTE (NEDGES + NNODES)
#define RSTRIDE 64      // fixed CSR row stride; P(deg+1 > 64) ~ 1e-20 for Poisson(16)
#define NBUCK 196       // buckets of 256 nodes: bucket = dst >> 8
#define NPB 256
#define BCAP 4864       // mean 4337, sigma ~66 -> +8 sigma
#define S1_EPT 16       // edges per thread in k_bin
#define BIN_BLOCKS ((TOTE + 4095) / 4096)   // 208
#define GSTRIDE 16      // gcnt padding: 1 counter per 64B line (cross-XCD atomic contention)
#define GEMM1_BLOCKS ((NNODES + 127) / 128) // 391

typedef __attribute__((ext_vector_type(8))) short short8;
typedef __attribute__((ext_vector_type(4))) float floatx4;

static __device__ __forceinline__ short f2bf(float f) {
    __hip_bfloat16 b = __float2bfloat16(f);
    return *reinterpret_cast<short*>(&b);
}

#define AS1 __attribute__((address_space(1)))
#define AS3 __attribute__((address_space(3)))

static __device__ __forceinline__ void ld_lds16(const void* g, void* l) {
#if __has_builtin(__builtin_amdgcn_global_load_lds)
    __builtin_amdgcn_global_load_lds((const AS1 void*)g, (AS3 void*)l, 16, 0, 0);
#endif
}

// ---------------- phase A: bin edges by dst>>8 (+ fused W1 pre-swizzle) --------

__global__ __launch_bounds__(256) void k_bin(const int* __restrict__ ei,
                                             int* __restrict__ gcnt, int* __restrict__ barr,
                                             const float* __restrict__ W,
                                             const float* __restrict__ a_s,
                                             const float* __restrict__ a_d,
                                             short* __restrict__ Wsw) {
    int tid = threadIdx.x;
    if (blockIdx.x >= BIN_BLOCKS) {
        int t = (blockIdx.x - BIN_BLOCKS) * 256 + tid;   // 4608 threads
        if (t >= 4608) return;
        short8 b;
        if (t < 4096) {
            int kc = t >> 9, nt = (t >> 6) & 7, lane = t & 63;
            int quad = lane >> 4, lo = lane & 15;
#pragma unroll
            for (int j = 0; j < 8; j++)
                b[j] = f2bf(W[(size_t)(kc * 32 + quad * 8 + j) * 128 + nt * 16 + lo]);
        } else {
            int t2 = t - 4096;
            int kc = t2 >> 6, lane = t2 & 63;
            int quad = lane >> 4, lo = lane & 15;
            int h = lo & 7;
            const float* av = (lo < 8) ? (a_s + h * 16) : (a_d + h * 16);
#pragma unroll
            for (int j = 0; j < 8; j++) {
                int k = kc * 32 + quad * 8 + j;
                float acc = 0.f;
#pragma unroll
                for (int c = 0; c < 16; c++) acc += W[(size_t)k * 128 + h * 16 + c] * av[c];
                b[j] = f2bf(acc);
            }
        }
        *(short8*)(Wsw + (size_t)t * 8) = b;
        return;
    }

    __shared__ int lcnt[NBUCK], lbase[NBUCK];
    if (tid < NBUCK) lcnt[tid] = 0;
    __syncthreads();
    int e0 = blockIdx.x * (256 * S1_EPT) + tid;
    int s[S1_EPT], d[S1_EPT], rk[S1_EPT];
#pragma unroll
    for (int k = 0; k < S1_EPT; k++) {
        int e = e0 + k * 256;
        bool v = e < TOTE;
        int ss = 0, dd = 0;
        if (v) {
            if (e < NEDGES) { ss = ei[e]; dd = ei[NEDGES + e]; }
            else            { ss = e - NEDGES; dd = ss; }
        }
        s[k] = ss; d[k] = dd;
        rk[k] = v ? atomicAdd(&lcnt[dd >> 8], 1) : -1;
    }
    __syncthreads();
    if (tid < NBUCK) lbase[tid] = lcnt[tid] ? atomicAdd(&gcnt[tid * GSTRIDE], lcnt[tid]) : 0;
    __syncthreads();
#pragma unroll
    for (int k = 0; k < S1_EPT; k++) {
        if (rk[k] >= 0) {
            int b = d[k] >> 8;
            int pos = lbase[b] + rk[k];
            if (pos < BCAP)
                barr[(size_t)b * BCAP + pos] = ((d[k] & 255) << 16) | s[k];
        }
    }
}

// ---------------- fused phase B: CSR build (blocks < NBUCK) + L1 GEMM ----------

__global__ __launch_bounds__(256) void k_mid(const int* __restrict__ gcnt,
                                             const int* __restrict__ barr,
                                             int* __restrict__ cnt, int* __restrict__ csr,
                                             const float* __restrict__ x,
                                             const short* __restrict__ Wsw,
                                             __hip_bfloat16* __restrict__ h1,
                                             float* __restrict__ as1, float* __restrict__ ad1) {
    __shared__ short smem[32768];   // 64 KB, shared by both paths
    int tid = threadIdx.x;

    if (blockIdx.x < NBUCK) {
        // ---- CSR path ----
        int* lcnt = (int*)smem;                         // 256 ints = 1 KB
        unsigned short* lcsr = (unsigned short*)smem + 512;  // 256*65 ushorts
        int b = blockIdx.x;
        lcnt[tid] = 0;
        __syncthreads();
        int n = min(gcnt[b * GSTRIDE], BCAP);
        int nodeBase = b << 8;
        for (int i = tid; i < n; i += 256) {
            int e = barr[(size_t)b * BCAP + i];
            int ln = e >> 16;
            int r = atomicAdd(&lcnt[ln], 1);
            if (r < RSTRIDE) lcsr[ln * 65 + r] = (unsigned short)(e & 0xFFFF);
        }
        __syncthreads();
        int node = nodeBase + tid;
        if (node < NNODES) cnt[node] = min(lcnt[tid], RSTRIDE);
        for (int i = tid; i < NPB * RSTRIDE; i += 256) {
            int ln = i >> 6;
            int nn = nodeBase + ln;
            if (nn < NNODES && (i & 63) < min(lcnt[ln], RSTRIDE))
                csr[(size_t)nodeBase * RSTRIDE + i] = (int)lcsr[ln * 65 + (i & 63)];
        }
        return;
    }

    // ---- GEMM1 path ----
    short* bsw = smem;
    int bid  = blockIdx.x - NBUCK;
    int wave = tid >> 6;
    int lane = tid & 63;
    int quad = lane >> 4;
    int lo   = lane & 15;

#if __has_builtin(__builtin_amdgcn_global_load_lds)
    {
        const char* gsrc = (const char*)Wsw + (size_t)wave * 1024 + (size_t)lane * 16;
        char* ldst = (char*)bsw + wave * 1024;
#pragma unroll
        for (int it = 0; it < 16; it++)
            ld_lds16(gsrc + it * 4096, ldst + it * 4096);
    }
#else
    {
        const uint4* g4 = (const uint4*)Wsw;
        uint4* l4 = (uint4*)bsw;
#pragma unroll
        for (int it = 0; it < 16; it++) l4[it * 256 + tid] = g4[it * 256 + tid];
    }
#endif
    short8 wafr[8];
#pragma unroll
    for (int kc = 0; kc < 8; kc++)
        wafr[kc] = *(const short8*)(Wsw + (size_t)(4096 + kc * 64 + lane) * 8);
    __syncthreads();

    int rowBase = bid * 128 + wave * 32;
    const float* xa[2];
#pragma unroll
    for (int mt = 0; mt < 2; mt++) {
        int row = rowBase + mt * 16 + lo;
        row = (row < NNODES) ? row : (NNODES - 1);
        xa[mt] = x + (size_t)row * 256 + quad * 8;
    }

    floatx4 acc[2][8], accA[2];
#pragma unroll
    for (int mt = 0; mt < 2; mt++) {
        accA[mt] = (floatx4){0.f, 0.f, 0.f, 0.f};
#pragma unroll
        for (int nt = 0; nt < 8; nt++) acc[mt][nt] = (floatx4){0.f, 0.f, 0.f, 0.f};
    }

    float4 a0[2], a1[2];
#pragma unroll
    for (int mt = 0; mt < 2; mt++) {
        a0[mt] = *(const float4*)(xa[mt]);
        a1[mt] = *(const float4*)(xa[mt] + 4);
    }

    for (int kc = 0; kc < 8; kc++) {
        float4 n0[2], n1[2];
        if (kc < 7) {
#pragma unroll
            for (int mt = 0; mt < 2; mt++) {
                n0[mt] = *(const float4*)(xa[mt] + (kc + 1) * 32);
                n1[mt] = *(const float4*)(xa[mt] + (kc + 1) * 32 + 4);
            }
        }
        short8 afr[2];
#pragma unroll
        for (int mt = 0; mt < 2; mt++) {
            union { short8 s; __hip_bfloat162 h[4]; } u;
            u.h[0] = __float22bfloat162_rn(make_float2(a0[mt].x, a0[mt].y));
            u.h[1] = __float22bfloat162_rn(make_float2(a0[mt].z, a0[mt].w));
            u.h[2] = __float22bfloat162_rn(make_float2(a1[mt].x, a1[mt].y));
            u.h[3] = __float22bfloat162_rn(make_float2(a1[mt].z, a1[mt].w));
            afr[mt] = u.s;
        }
#pragma unroll
        for (int nt = 0; nt < 8; nt++) {
            short8 bfr = *(const short8*)&bsw[((kc * 8 + nt) * 64 + lane) * 8];
            acc[0][nt] = __builtin_amdgcn_mfma_f32_16x16x32_bf16(afr[0], bfr, acc[0][nt], 0, 0, 0);
            acc[1][nt] = __builtin_amdgcn_mfma_f32_16x16x32_bf16(afr[1], bfr, acc[1][nt], 0, 0, 0);
        }
        accA[0] = __builtin_amdgcn_mfma_f32_16x16x32_bf16(afr[0], wafr[kc], accA[0], 0, 0, 0);
        accA[1] = __builtin_amdgcn_mfma_f32_16x16x32_bf16(afr[1], wafr[kc], accA[1], 0, 0, 0);
#pragma unroll
        for (int mt = 0; mt < 2; mt++) { a0[mt] = n0[mt]; a1[mt] = n1[mt]; }
    }

#pragma unroll
    for (int mt = 0; mt < 2; mt++)
#pragma unroll
        for (int nt = 0; nt < 8; nt++)
#pragma unroll
            for (int reg = 0; reg < 4; reg++) {
                int row = rowBase + mt * 16 + quad * 4 + reg;
                int col = nt * 16 + lo;
                if (row < NNODES)
                    h1[(size_t)row * 128 + col] = __float2bfloat16(acc[mt][nt][reg]);
            }
#pragma unroll
    for (int mt = 0; mt < 2; mt++)
#pragma unroll
        for (int reg = 0; reg < 4; reg++) {
            int row = rowBase + mt * 16 + quad * 4 + reg;
            if (row < NNODES) {
                float v = accA[mt][reg];
                if (lo < 8) as1[(size_t)row * 8 + lo] = v;
                else        ad1[(size_t)row * 8 + (lo - 8)] = v;
            }
        }
}

// ---------------- fused layer-1 aggregate + ELU + layer-2 GEMM + alpha2 --------
// Round-15: R13's wave-independent zero-barrier-in-hot-path structure, with the
// per-node GLOBAL epilogue traffic removed (diagnosis: R13's 8 W2 float4 global
// loads per node-wave = ~700k extra VMEM requests interleaved into the gather
// stream, competing for L1/L2 ports and VMEM queue slots -> gather MLP diluted,
// hbm 3.0 -> 1.55 TB/s; regression tracked epilogue *global traffic* across
// R2/R3/R13, not epilogue VALU length). W2 now staged to LDS once per block
// with ONE __syncthreads BEFORE the gather loop (no degree coupling). The
// epilogue read w2s[(cl*8+q)*16 + slot*4] as ds_read_b128 is conflict-free:
// 16 cl-lanes broadcast same address; 4 slots hit 4 disjoint bank quads.

__global__ __launch_bounds__(256) void k_aggA(const int* __restrict__ cnt, const int* __restrict__ csr,
                                              const __hip_bfloat16* __restrict__ h1,
                                              const float* __restrict__ as1, const float* __restrict__ ad1,
                                              const float* __restrict__ b1,
                                              const float* __restrict__ W2,
                                              const float* __restrict__ a_s2,
                                              const float* __restrict__ a_d2,
                                              float* __restrict__ h2,
                                              float* __restrict__ as2, float* __restrict__ ad2) {
    __shared__ float w2s[2048];                        // W2 [128][16] row-major, 8 KB
    int tid  = threadIdx.x;
#pragma unroll
    for (int i = 0; i < 8; i++) w2s[i * 256 + tid] = W2[i * 256 + tid];
    __syncthreads();                                   // before gather: no degree coupling

    int node = blockIdx.x * 4 + (tid >> 6);            // 1 node / wave; grid exact
    int lane = tid & 63;
    int cl   = lane & 15;                              // channel-slice (8 ch)
    int slot = lane >> 4;                              // edge slot 0..3
    int head = cl >> 1;
    int deg  = min(cnt[node], RSTRIDE);                // wave-uniform
    float adst = ad1[node * 8 + head];
    int rowv = csr[node * RSTRIDE + lane];             // full row, one coalesced load

    float acc[8] = {0.f, 0.f, 0.f, 0.f, 0.f, 0.f, 0.f, 0.f};
    float s = 0.f;
    for (int i2 = 0; i2 < deg; i2 += 16) {             // 16 edges/trip, 4 per slot
        float p[4];
        union { short8 v; __hip_bfloat162 h[4]; } u[4];
#pragma unroll
        for (int t = 0; t < 4; t++) {
            int ii = i2 + slot + t * 4;
            int src = __shfl(rowv, ii & 63);
            p[t] = 0.f;
            u[t].v = (short8){0, 0, 0, 0, 0, 0, 0, 0};
            if (ii < deg) {
                u[t].v = *(const short8*)(h1 + (size_t)src * 128 + cl * 8);
                float e = as1[src * 8 + head] + adst;
                e = (e > 0.f) ? e : NEG_SLOPE * e;
                p[t] = __expf(e);
            }
        }
        s += (p[0] + p[1]) + (p[2] + p[3]);
#pragma unroll
        for (int t = 0; t < 4; t++)
#pragma unroll
            for (int q = 0; q < 4; q++) {
                float2 f = __bfloat1622float2(u[t].h[q]);
                acc[q * 2]     = fmaf(p[t], f.x, acc[q * 2]);
                acc[q * 2 + 1] = fmaf(p[t], f.y, acc[q * 2 + 1]);
            }
    }

    // cross-slot reduction (slots live in lane bits 4,5) -> ALL lanes complete
#pragma unroll
    for (int q = 0; q < 8; q++) {
        acc[q] += __shfl_xor(acc[q], 16);
        acc[q] += __shfl_xor(acc[q], 32);
    }
    s += __shfl_xor(s, 16);
    s += __shfl_xor(s, 32);

    // all lanes: softmax-normalize + bias + ELU for channels cl*8..cl*8+7
    float is = 1.f / s;
    float4 b1a = *(const float4*)(b1 + cl * 8);
    float4 b1b = *(const float4*)(b1 + cl * 8 + 4);
    float v[8];
    v[0] = acc[0] * is + b1a.x; v[1] = acc[1] * is + b1a.y;
    v[2] = acc[2] * is + b1a.z; v[3] = acc[3] * is + b1a.w;
    v[4] = acc[4] * is + b1b.x; v[5] = acc[5] * is + b1b.y;
    v[6] = acc[6] * is + b1b.z; v[7] = acc[7] * is + b1b.w;
#pragma unroll
    for (int q = 0; q < 8; q++) v[q] = (v[q] > 0.f) ? v[q] : (__expf(v[q]) - 1.f);

    // in-register layer-2 GEMM from LDS W2: k=cl*8+q, outputs slot*4..slot*4+3
    float4 part = make_float4(0.f, 0.f, 0.f, 0.f);
#pragma unroll
    for (int q = 0; q < 8; q++) {
        float4 wrow = *(const float4*)(&w2s[(cl * 8 + q) * 16 + slot * 4]);
        part.x = fmaf(v[q], wrow.x, part.x);
        part.y = fmaf(v[q], wrow.y, part.y);
        part.z = fmaf(v[q], wrow.z, part.z);
        part.w = fmaf(v[q], wrow.w, part.w);
    }
    // reduce over the cl-group (lane bits 0..3: xor 1,2,4,8 -> DPP-cheap)
#pragma unroll
    for (int o = 1; o <= 8; o <<= 1) {
        part.x += __shfl_xor(part.x, o);
        part.y += __shfl_xor(part.y, o);
        part.z += __shfl_xor(part.z, o);
        part.w += __shfl_xor(part.w, o);
    }
    // each lane now holds h2[slot*4..slot*4+3]
    if (cl == 0) *(float4*)(h2 + (size_t)node * 16 + slot * 4) = part;

    float4 asv = *(const float4*)(a_s2 + slot * 4);
    float4 adv = *(const float4*)(a_d2 + slot * 4);
    float sv = part.x * asv.x + part.y * asv.y + part.z * asv.z + part.w * asv.w;
    float dv = part.x * adv.x + part.y * adv.y + part.z * adv.z + part.w * adv.w;
    sv += __shfl_xor(sv, 16); sv += __shfl_xor(sv, 32);
    dv += __shfl_xor(dv, 16); dv += __shfl_xor(dv, 32);
    if (lane == 0) { as2[node] = sv; ad2[node] = dv; }
}

// ---------------- layer-2 softmax-aggregate + bias ------------------------------

__global__ __launch_bounds__(256) void k_agg2(const int* __restrict__ cnt, const int* __restrict__ csr,
                                              const float* __restrict__ h2, const float* __restrict__ as2,
                                              const float* __restrict__ ad2, const float* __restrict__ b2,
                                              float* __restrict__ out) {
    int node = blockIdx.x * 4 + (threadIdx.x >> 6);
    int lane = threadIdx.x & 63;
    int c4   = lane & 3;                               // channel quarter (4 floats)
    int slot = lane >> 2;                              // edge slot 0..15
    int deg  = min(cnt[node], RSTRIDE);                // wave-uniform
    float adst = ad2[node];
    int rowv = csr[node * RSTRIDE + lane];

    float4 acc = make_float4(0.f, 0.f, 0.f, 0.f);
    float s = 0.f;
    for (int i2 = 0; i2 < deg; i2 += 32) {             // 32 edges/trip, 2 per slot
        int ia = i2 + slot;
        int ib = ia + 16;
        int sa = __shfl(rowv, ia & 63);
        int sb = __shfl(rowv, ib & 63);
        float p0 = 0.f, p1 = 0.f;
        float4 r0 = make_float4(0.f, 0.f, 0.f, 0.f);
        float4 r1 = make_float4(0.f, 0.f, 0.f, 0.f);
        if (ia < deg) {
            r0 = *(const float4*)(h2 + (size_t)sa * 16 + c4 * 4);
            float e = as2[sa] + adst;
            e = (e > 0.f) ? e : NEG_SLOPE * e;
            p0 = __expf(e);
        }
        if (ib < deg) {
            r1 = *(const float4*)(h2 + (size_t)sb * 16 + c4 * 4);
            float e = as2[sb] + adst;
            e = (e > 0.f) ? e : NEG_SLOPE * e;
            p1 = __expf(e);
        }
        s += p0 + p1;
        acc.x = fmaf(p0, r0.x, fmaf(p1, r1.x, acc.x));
        acc.y = fmaf(p0, r0.y, fmaf(p1, r1.y, acc.y));
        acc.z = fmaf(p0, r0.z, fmaf(p1, r1.z, acc.z));
        acc.w = fmaf(p0, r0.w, fmaf(p1, r1.w, acc.w));
    }
#pragma unroll
    for (int o = 4; o <= 32; o <<= 1) {                // reduce over 16 slots
        acc.x += __shfl_xor(acc.x, o);
        acc.y += __shfl_xor(acc.y, o);
        acc.z += __shfl_xor(acc.z, o);
        acc.w += __shfl_xor(acc.w, o);
        s += __shfl_xor(s, o);
    }
    if (slot == 0) {
        float is = 1.f / s;
        float4 o4;
        o4.x = acc.x * is + b2[c4 * 4 + 0];
        o4.y = acc.y * is + b2[c4 * 4 + 1];
        o4.z = acc.z * is + b2[c4 * 4 + 2];
        o4.w = acc.w * is + b2[c4 * 4 + 3];
        *(float4*)(out + (size_t)node * 16 + c4 * 4) = o4;
    }
}

// ---------------- launch ----------------

extern "C" void kernel_launch(void* const* d_in, const int* in_sizes, int n_in,
                              void* d_out, int out_size, void* d_ws, size_t ws_size,
                              hipStream_t stream) {
    const float* x    = (const float*)d_in[0];
    const int*   ei   = (const int*)d_in[1];
    const float* W1   = (const float*)d_in[2];
    const float* a_s1 = (const float*)d_in[3];
    const float* a_d1 = (const float*)d_in[4];
    const float* b1   = (const float*)d_in[5];
    const float* W2   = (const float*)d_in[6];
    const float* a_s2 = (const float*)d_in[7];
    const float* a_d2 = (const float*)d_in[8];
    const float* b2   = (const float*)d_in[9];
    float* out = (float*)d_out;

    char* p = (char*)d_ws;
    auto alloc = [&](size_t bytes) -> char* {
        char* q = p;
        p += (bytes + 255) & ~(size_t)255;
        return q;
    };
    int*  gcnt = (int*)alloc((size_t)NBUCK * GSTRIDE * 4);        // 12.5 KB, padded
    int*  barr = (int*)alloc((size_t)NBUCK * BCAP * 4);           // 3.8 MB, dead after k_mid
    int*  cnt  = (int*)alloc((size_t)NNODES * 4);
    int*  csr  = (int*)alloc((size_t)NNODES * RSTRIDE * 4);       // 12.8 MB
    short* Wsw = (short*)alloc((size_t)36864 * 2);                // 8 B-tiles + Wa tile
    __hip_bfloat16* h1 = (__hip_bfloat16*)alloc((size_t)NNODES * 128 * 2);
    float* as1 = (float*)alloc((size_t)NNODES * 8 * 4);
    float* ad1 = (float*)alloc((size_t)NNODES * 8 * 4);
    float* h2  = (float*)alloc((size_t)NNODES * 16 * 4);          // own region: as1/ad1 are
                                                                  // live concurrently in k_aggA
    // aliases (regions dead by the time these are written):
    float* as2 = (float*)barr;           // over barr (dead after k_mid)
    float* ad2 = (float*)barr + NNODES;

    hipMemsetAsync(gcnt, 0, (size_t)NBUCK * GSTRIDE * 4, stream);
    hipLaunchKernelGGL(k_bin,   dim3(BIN_BLOCKS + 18), dim3(256), 0, stream,
                       ei, gcnt, barr, W1, a_s1, a_d1, Wsw);
    hipLaunchKernelGGL(k_mid,   dim3(NBUCK + GEMM1_BLOCKS), dim3(256), 0, stream,
                       gcnt, barr, cnt, csr, x, Wsw, h1, as1, ad1);
    hipLaunchKernelGGL(k_aggA,  dim3(NNODES / 4), dim3(256), 0, stream,
                       cnt, csr, h1, as1, ad1, b1, W2, a_s2, a_d2, h2, as2, ad2);
    hipLaunchKernelGGL(k_agg2,  dim3(NNODES / 4), dim3(256), 0, stream, cnt, csr, h2, as2, ad2, b2, out);
}

// Round 8
// 208.631 us; speedup vs baseline: 1.0741x; 1.0101x over previous
//
#include <hip/hip_runtime.h>
#include <hip/hip_bf16.h>

#define NNODES 50000
#define NEDGES 800000
#define NFEATS 256
#define NHID 16
#define HEADS 8
#define NCLS 16
#define NEG_SLOPE 0.2f
#define TOTE (NEDGES + NNODES)
#define RSTRIDE 64      // fixed CSR row stride; P(deg+1 > 64) ~ 1e-20 for Poisson(16)
#define NBUCK 196       // buckets of 256 nodes: bucket = dst >> 8
#define NPB 256
#define BCAP 4864       // mean 4337, sigma ~66 -> +8 sigma
#define S1_EPT 16       // edges per thread in k_bin
#define BIN_BLOCKS ((TOTE + 4095) / 4096)   // 208
#define GSTRIDE 16      // gcnt padding: 1 counter per 64B line (cross-XCD atomic contention)
#define GEMM1_BLOCKS ((NNODES + 127) / 128) // 391

typedef __attribute__((ext_vector_type(8))) short short8;
typedef __attribute__((ext_vector_type(4))) float floatx4;

static __device__ __forceinline__ short f2bf(float f) {
    __hip_bfloat16 b = __float2bfloat16(f);
    return *reinterpret_cast<short*>(&b);
}

#define AS1 __attribute__((address_space(1)))
#define AS3 __attribute__((address_space(3)))

static __device__ __forceinline__ void ld_lds16(const void* g, void* l) {
#if __has_builtin(__builtin_amdgcn_global_load_lds)
    __builtin_amdgcn_global_load_lds((const AS1 void*)g, (AS3 void*)l, 16, 0, 0);
#endif
}

// ---------------- phase A: bin edges by dst>>8 (+ fused W1 pre-swizzle) --------

__global__ __launch_bounds__(256) void k_bin(const int* __restrict__ ei,
                                             int* __restrict__ gcnt, int* __restrict__ barr,
                                             const float* __restrict__ W,
                                             const float* __restrict__ a_s,
                                             const float* __restrict__ a_d,
                                             short* __restrict__ Wsw) {
    int tid = threadIdx.x;
    if (blockIdx.x >= BIN_BLOCKS) {
        int t = (blockIdx.x - BIN_BLOCKS) * 256 + tid;   // 4608 threads
        if (t >= 4608) return;
        short8 b;
        if (t < 4096) {
            int kc = t >> 9, nt = (t >> 6) & 7, lane = t & 63;
            int quad = lane >> 4, lo = lane & 15;
#pragma unroll
            for (int j = 0; j < 8; j++)
                b[j] = f2bf(W[(size_t)(kc * 32 + quad * 8 + j) * 128 + nt * 16 + lo]);
        } else {
            int t2 = t - 4096;
            int kc = t2 >> 6, lane = t2 & 63;
            int quad = lane >> 4, lo = lane & 15;
            int h = lo & 7;
            const float* av = (lo < 8) ? (a_s + h * 16) : (a_d + h * 16);
#pragma unroll
            for (int j = 0; j < 8; j++) {
                int k = kc * 32 + quad * 8 + j;
                float acc = 0.f;
#pragma unroll
                for (int c = 0; c < 16; c++) acc += W[(size_t)k * 128 + h * 16 + c] * av[c];
                b[j] = f2bf(acc);
            }
        }
        *(short8*)(Wsw + (size_t)t * 8) = b;
        return;
    }

    __shared__ int lcnt[NBUCK], lbase[NBUCK];
    if (tid < NBUCK) lcnt[tid] = 0;
    __syncthreads();
    int e0 = blockIdx.x * (256 * S1_EPT) + tid;
    int s[S1_EPT], d[S1_EPT], rk[S1_EPT];
#pragma unroll
    for (int k = 0; k < S1_EPT; k++) {
        int e = e0 + k * 256;
        bool v = e < TOTE;
        int ss = 0, dd = 0;
        if (v) {
            if (e < NEDGES) { ss = ei[e]; dd = ei[NEDGES + e]; }
            else            { ss = e - NEDGES; dd = ss; }
        }
        s[k] = ss; d[k] = dd;
        rk[k] = v ? atomicAdd(&lcnt[dd >> 8], 1) : -1;
    }
    __syncthreads();
    if (tid < NBUCK) lbase[tid] = lcnt[tid] ? atomicAdd(&gcnt[tid * GSTRIDE], lcnt[tid]) : 0;
    __syncthreads();
#pragma unroll
    for (int k = 0; k < S1_EPT; k++) {
        if (rk[k] >= 0) {
            int b = d[k] >> 8;
            int pos = lbase[b] + rk[k];
            if (pos < BCAP)
                barr[(size_t)b * BCAP + pos] = ((d[k] & 255) << 16) | s[k];
        }
    }
}

// ---------------- fused phase B: CSR build (blocks < NBUCK) + L1 GEMM ----------

__global__ __launch_bounds__(256) void k_mid(const int* __restrict__ gcnt,
                                             const int* __restrict__ barr,
                                             int* __restrict__ cnt, unsigned short* __restrict__ csr,
                                             const float* __restrict__ x,
                                             const short* __restrict__ Wsw,
                                             __hip_bfloat16* __restrict__ h1,
                                             float* __restrict__ as1, float* __restrict__ ad1) {
    __shared__ short smem[32768];   // 64 KB, shared by both paths
    int tid = threadIdx.x;

    if (blockIdx.x < NBUCK) {
        // ---- CSR path ----
        int* lcnt = (int*)smem;                         // 256 ints = 1 KB
        unsigned short* lcsr = (unsigned short*)smem + 512;  // 256*65 ushorts
        int b = blockIdx.x;
        lcnt[tid] = 0;
        __syncthreads();
        int n = min(gcnt[b * GSTRIDE], BCAP);
        int nodeBase = b << 8;
        for (int i = tid; i < n; i += 256) {
            int e = barr[(size_t)b * BCAP + i];
            int ln = e >> 16;
            int r = atomicAdd(&lcnt[ln], 1);
            if (r < RSTRIDE) lcsr[ln * 65 + r] = (unsigned short)(e & 0xFFFF);
        }
        __syncthreads();
        int node = nodeBase + tid;
        if (node < NNODES) cnt[node] = min(lcnt[tid], RSTRIDE);
        for (int i = tid; i < NPB * RSTRIDE; i += 256) {
            int ln = i >> 6;
            int nn = nodeBase + ln;
            if (nn < NNODES && (i & 63) < min(lcnt[ln], RSTRIDE))
                csr[(size_t)nodeBase * RSTRIDE + i] = lcsr[ln * 65 + (i & 63)];
        }
        return;
    }

    // ---- GEMM1 path ----
    short* bsw = smem;
    int bid  = blockIdx.x - NBUCK;
    int wave = tid >> 6;
    int lane = tid & 63;
    int quad = lane >> 4;
    int lo   = lane & 15;

#if __has_builtin(__builtin_amdgcn_global_load_lds)
    {
        const char* gsrc = (const char*)Wsw + (size_t)wave * 1024 + (size_t)lane * 16;
        char* ldst = (char*)bsw + wave * 1024;
#pragma unroll
        for (int it = 0; it < 16; it++)
            ld_lds16(gsrc + it * 4096, ldst + it * 4096);
    }
#else
    {
        const uint4* g4 = (const uint4*)Wsw;
        uint4* l4 = (uint4*)bsw;
#pragma unroll
        for (int it = 0; it < 16; it++) l4[it * 256 + tid] = g4[it * 256 + tid];
    }
#endif
    short8 wafr[8];
#pragma unroll
    for (int kc = 0; kc < 8; kc++)
        wafr[kc] = *(const short8*)(Wsw + (size_t)(4096 + kc * 64 + lane) * 8);
    __syncthreads();

    int rowBase = bid * 128 + wave * 32;
    const float* xa[2];
#pragma unroll
    for (int mt = 0; mt < 2; mt++) {
        int row = rowBase + mt * 16 + lo;
        row = (row < NNODES) ? row : (NNODES - 1);
        xa[mt] = x + (size_t)row * 256 + quad * 8;
    }

    floatx4 acc[2][8], accA[2];
#pragma unroll
    for (int mt = 0; mt < 2; mt++) {
        accA[mt] = (floatx4){0.f, 0.f, 0.f, 0.f};
#pragma unroll
        for (int nt = 0; nt < 8; nt++) acc[mt][nt] = (floatx4){0.f, 0.f, 0.f, 0.f};
    }

    float4 a0[2], a1[2];
#pragma unroll
    for (int mt = 0; mt < 2; mt++) {
        a0[mt] = *(const float4*)(xa[mt]);
        a1[mt] = *(const float4*)(xa[mt] + 4);
    }

    for (int kc = 0; kc < 8; kc++) {
        float4 n0[2], n1[2];
        if (kc < 7) {
#pragma unroll
            for (int mt = 0; mt < 2; mt++) {
                n0[mt] = *(const float4*)(xa[mt] + (kc + 1) * 32);
                n1[mt] = *(const float4*)(xa[mt] + (kc + 1) * 32 + 4);
            }
        }
        short8 afr[2];
#pragma unroll
        for (int mt = 0; mt < 2; mt++) {
            union { short8 s; __hip_bfloat162 h[4]; } u;
            u.h[0] = __float22bfloat162_rn(make_float2(a0[mt].x, a0[mt].y));
            u.h[1] = __float22bfloat162_rn(make_float2(a0[mt].z, a0[mt].w));
            u.h[2] = __float22bfloat162_rn(make_float2(a1[mt].x, a1[mt].y));
            u.h[3] = __float22bfloat162_rn(make_float2(a1[mt].z, a1[mt].w));
            afr[mt] = u.s;
        }
#pragma unroll
        for (int nt = 0; nt < 8; nt++) {
            short8 bfr = *(const short8*)&bsw[((kc * 8 + nt) * 64 + lane) * 8];
            acc[0][nt] = __builtin_amdgcn_mfma_f32_16x16x32_bf16(afr[0], bfr, acc[0][nt], 0, 0, 0);
            acc[1][nt] = __builtin_amdgcn_mfma_f32_16x16x32_bf16(afr[1], bfr, acc[1][nt], 0, 0, 0);
        }
        accA[0] = __builtin_amdgcn_mfma_f32_16x16x32_bf16(afr[0], wafr[kc], accA[0], 0, 0, 0);
        accA[1] = __builtin_amdgcn_mfma_f32_16x16x32_bf16(afr[1], wafr[kc], accA[1], 0, 0, 0);
#pragma unroll
        for (int mt = 0; mt < 2; mt++) { a0[mt] = n0[mt]; a1[mt] = n1[mt]; }
    }

#pragma unroll
    for (int mt = 0; mt < 2; mt++)
#pragma unroll
        for (int nt = 0; nt < 8; nt++)
#pragma unroll
            for (int reg = 0; reg < 4; reg++) {
                int row = rowBase + mt * 16 + quad * 4 + reg;
                int col = nt * 16 + lo;
                if (row < NNODES)
                    h1[(size_t)row * 128 + col] = __float2bfloat16(acc[mt][nt][reg]);
            }
#pragma unroll
    for (int mt = 0; mt < 2; mt++)
#pragma unroll
        for (int reg = 0; reg < 4; reg++) {
            int row = rowBase + mt * 16 + quad * 4 + reg;
            if (row < NNODES) {
                float v = accA[mt][reg];
                if (lo < 8) as1[(size_t)row * 8 + lo] = v;
                else        ad1[(size_t)row * 8 + (lo - 8)] = v;
            }
        }
}

// ---------------- fused layer-1 aggregate + ELU + layer-2 GEMM + alpha2 --------
// Round-16 (resubmit; R7 was an infra failure, not a kernel fault): fix R5's
// 16-way LDS conflict (11.2M cycles = ~18us/CU of LDS-pipe occupancy, the
// measured +21us epilogue cost). The (k=cl-strided, c=slot) W2 read can never
// beat 8-way (bank fn factors through (cl%4, slot)), so TRANSPOSE the lane
// roles: lane (slot,cl) computes out[cl] over k-quarter slot*32..+31; v comes
// via __shfl (conflict-free), W2 via stride-17 padded LDS:
// bank = (16*slot + 17j + cl) % 32 -> 2-way max (free, m136).
// csr is now ushort (src < 50000 < 2^16): halves csr traffic everywhere.

__global__ __launch_bounds__(256) void k_aggA(const int* __restrict__ cnt,
                                              const unsigned short* __restrict__ csr,
                                              const __hip_bfloat16* __restrict__ h1,
                                              const float* __restrict__ as1, const float* __restrict__ ad1,
                                              const float* __restrict__ b1,
                                              const float* __restrict__ W2,
                                              const float* __restrict__ a_s2,
                                              const float* __restrict__ a_d2,
                                              float* __restrict__ h2,
                                              float* __restrict__ as2, float* __restrict__ ad2) {
    __shared__ float w2s[2176];                        // W2 [128][17-padded], 8.5 KB
    int tid  = threadIdx.x;
#pragma unroll
    for (int i = 0; i < 8; i++) {
        int e = i * 256 + tid;
        w2s[(e >> 4) * 17 + (e & 15)] = W2[e];
    }
    __syncthreads();                                   // before gather: no degree coupling

    int node = blockIdx.x * 4 + (tid >> 6);            // 1 node / wave; grid exact
    int lane = tid & 63;
    int cl   = lane & 15;                              // channel-slice (8 ch)
    int slot = lane >> 4;                              // edge slot 0..3
    int head = cl >> 1;
    int deg  = min(cnt[node], RSTRIDE);                // wave-uniform
    float adst = ad1[node * 8 + head];
    int rowv = csr[node * RSTRIDE + lane];             // full row, one coalesced load

    float acc[8] = {0.f, 0.f, 0.f, 0.f, 0.f, 0.f, 0.f, 0.f};
    float s = 0.f;
    for (int i2 = 0; i2 < deg; i2 += 16) {             // 16 edges/trip, 4 per slot
        float p[4];
        union { short8 v; __hip_bfloat162 h[4]; } u[4];
#pragma unroll
        for (int t = 0; t < 4; t++) {
            int ii = i2 + slot + t * 4;
            int src = __shfl(rowv, ii & 63);
            p[t] = 0.f;
            u[t].v = (short8){0, 0, 0, 0, 0, 0, 0, 0};
            if (ii < deg) {
                u[t].v = *(const short8*)(h1 + (size_t)src * 128 + cl * 8);
                float e = as1[src * 8 + head] + adst;
                e = (e > 0.f) ? e : NEG_SLOPE * e;
                p[t] = __expf(e);
            }
        }
        s += (p[0] + p[1]) + (p[2] + p[3]);
#pragma unroll
        for (int t = 0; t < 4; t++)
#pragma unroll
            for (int q = 0; q < 4; q++) {
                float2 f = __bfloat1622float2(u[t].h[q]);
                acc[q * 2]     = fmaf(p[t], f.x, acc[q * 2]);
                acc[q * 2 + 1] = fmaf(p[t], f.y, acc[q * 2 + 1]);
            }
    }

    // cross-slot reduction (slots live in lane bits 4,5) -> ALL lanes complete
#pragma unroll
    for (int q = 0; q < 8; q++) {
        acc[q] += __shfl_xor(acc[q], 16);
        acc[q] += __shfl_xor(acc[q], 32);
    }
    s += __shfl_xor(s, 16);
    s += __shfl_xor(s, 32);

    // all lanes: softmax-normalize + bias + ELU for channels cl*8..cl*8+7
    float is = 1.f / s;
    float4 b1a = *(const float4*)(b1 + cl * 8);
    float4 b1b = *(const float4*)(b1 + cl * 8 + 4);
    float v[8];
    v[0] = acc[0] * is + b1a.x; v[1] = acc[1] * is + b1a.y;
    v[2] = acc[2] * is + b1a.z; v[3] = acc[3] * is + b1a.w;
    v[4] = acc[4] * is + b1b.x; v[5] = acc[5] * is + b1b.y;
    v[6] = acc[6] * is + b1b.z; v[7] = acc[7] * is + b1b.w;
#pragma unroll
    for (int q = 0; q < 8; q++) v[q] = (v[q] > 0.f) ? v[q] : (__expf(v[q]) - 1.f);

    // layer-2 GEMM, lane-transposed: lane (slot,cl) -> out[cl], k in slot*32..+31.
    // vk via shfl (v replicated across slots); wk via stride-17 LDS (2-way max).
    float outp = 0.f;
#pragma unroll
    for (int j = 0; j < 32; j++) {
        float vk = __shfl(v[j & 7], slot * 4 + (j >> 3));
        float wk = w2s[(slot * 32 + j) * 17 + cl];
        outp = fmaf(vk, wk, outp);
    }
    outp += __shfl_xor(outp, 16);
    outp += __shfl_xor(outp, 32);                      // full h2[cl] in every lane
    if (slot == 0) h2[(size_t)node * 16 + cl] = outp;  // 16 lanes, one 64B line

    float sv = outp * a_s2[cl];
    float dv = outp * a_d2[cl];
#pragma unroll
    for (int o = 1; o <= 8; o <<= 1) {
        sv += __shfl_xor(sv, o);
        dv += __shfl_xor(dv, o);
    }
    if (lane == 0) { as2[node] = sv; ad2[node] = dv; }
}

// ---------------- layer-2 softmax-aggregate + bias ------------------------------

__global__ __launch_bounds__(256) void k_agg2(const int* __restrict__ cnt,
                                              const unsigned short* __restrict__ csr,
                                              const float* __restrict__ h2, const float* __restrict__ as2,
                                              const float* __restrict__ ad2, const float* __restrict__ b2,
                                              float* __restrict__ out) {
    int node = blockIdx.x * 4 + (threadIdx.x >> 6);
    int lane = threadIdx.x & 63;
    int c4   = lane & 3;                               // channel quarter (4 floats)
    int slot = lane >> 2;                              // edge slot 0..15
    int deg  = min(cnt[node], RSTRIDE);                // wave-uniform
    float adst = ad2[node];
    int rowv = csr[node * RSTRIDE + lane];

    float4 acc = make_float4(0.f, 0.f, 0.f, 0.f);
    float s = 0.f;
    for (int i2 = 0; i2 < deg; i2 += 32) {             // 32 edges/trip, 2 per slot
        int ia = i2 + slot;
        int ib = ia + 16;
        int sa = __shfl(rowv, ia & 63);
        int sb = __shfl(rowv, ib & 63);
        float p0 = 0.f, p1 = 0.f;
        float4 r0 = make_float4(0.f, 0.f, 0.f, 0.f);
        float4 r1 = make_float4(0.f, 0.f, 0.f, 0.f);
        if (ia < deg) {
            r0 = *(const float4*)(h2 + (size_t)sa * 16 + c4 * 4);
            float e = as2[sa] + adst;
            e = (e > 0.f) ? e : NEG_SLOPE * e;
            p0 = __expf(e);
        }
        if (ib < deg) {
            r1 = *(const float4*)(h2 + (size_t)sb * 16 + c4 * 4);
            float e = as2[sb] + adst;
            e = (e > 0.f) ? e : NEG_SLOPE * e;
            p1 = __expf(e);
        }
        s += p0 + p1;
        acc.x = fmaf(p0, r0.x, fmaf(p1, r1.x, acc.x));
        acc.y = fmaf(p0, r0.y, fmaf(p1, r1.y, acc.y));
        acc.z = fmaf(p0, r0.z, fmaf(p1, r1.z, acc.z));
        acc.w = fmaf(p0, r0.w, fmaf(p1, r1.w, acc.w));
    }
#pragma unroll
    for (int o = 4; o <= 32; o <<= 1) {                // reduce over 16 slots
        acc.x += __shfl_xor(acc.x, o);
        acc.y += __shfl_xor(acc.y, o);
        acc.z += __shfl_xor(acc.z, o);
        acc.w += __shfl_xor(acc.w, o);
        s += __shfl_xor(s, o);
    }
    if (slot == 0) {
        float is = 1.f / s;
        float4 o4;
        o4.x = acc.x * is + b2[c4 * 4 + 0];
        o4.y = acc.y * is + b2[c4 * 4 + 1];
        o4.z = acc.z * is + b2[c4 * 4 + 2];
        o4.w = acc.w * is + b2[c4 * 4 + 3];
        *(float4*)(out + (size_t)node * 16 + c4 * 4) = o4;
    }
}

// ---------------- launch ----------------

extern "C" void kernel_launch(void* const* d_in, const int* in_sizes, int n_in,
                              void* d_out, int out_size, void* d_ws, size_t ws_size,
                              hipStream_t stream) {
    const float* x    = (const float*)d_in[0];
    const int*   ei   = (const int*)d_in[1];
    const float* W1   = (const float*)d_in[2];
    const float* a_s1 = (const float*)d_in[3];
    const float* a_d1 = (const float*)d_in[4];
    const float* b1   = (const float*)d_in[5];
    const float* W2   = (const float*)d_in[6];
    const float* a_s2 = (const float*)d_in[7];
    const float* a_d2 = (const float*)d_in[8];
    const float* b2   = (const float*)d_in[9];
    float* out = (float*)d_out;

    char* p = (char*)d_ws;
    auto alloc = [&](size_t bytes) -> char* {
        char* q = p;
        p += (bytes + 255) & ~(size_t)255;
        return q;
    };
    int*  gcnt = (int*)alloc((size_t)NBUCK * GSTRIDE * 4);        // 12.5 KB, padded
    int*  barr = (int*)alloc((size_t)NBUCK * BCAP * 4);           // 3.8 MB, dead after k_mid
    int*  cnt  = (int*)alloc((size_t)NNODES * 4);
    unsigned short* csr = (unsigned short*)alloc((size_t)NNODES * RSTRIDE * 2);  // 6.4 MB (ushort)
    short* Wsw = (short*)alloc((size_t)36864 * 2);                // 8 B-tiles + Wa tile
    __hip_bfloat16* h1 = (__hip_bfloat16*)alloc((size_t)NNODES * 128 * 2);
    float* as1 = (float*)alloc((size_t)NNODES * 8 * 4);
    float* ad1 = (float*)alloc((size_t)NNODES * 8 * 4);
    float* h2  = (float*)alloc((size_t)NNODES * 16 * 4);          // own region: as1/ad1 are
                                                                  // live concurrently in k_aggA
    // aliases (regions dead by the time these are written):
    float* as2 = (float*)barr;           // over barr (dead after k_mid)
    float* ad2 = (float*)barr + NNODES;

    hipMemsetAsync(gcnt, 0, (size_t)NBUCK * GSTRIDE * 4, stream);
    hipLaunchKernelGGL(k_bin,   dim3(BIN_BLOCKS + 18), dim3(256), 0, stream,
                       ei, gcnt, barr, W1, a_s1, a_d1, Wsw);
    hipLaunchKernelGGL(k_mid,   dim3(NBUCK + GEMM1_BLOCKS), dim3(256), 0, stream,
                       gcnt, barr, cnt, csr, x, Wsw, h1, as1, ad1);
    hipLaunchKernelGGL(k_aggA,  dim3(NNODES / 4), dim3(256), 0, stream,
                       cnt, csr, h1, as1, ad1, b1, W2, a_s2, a_d2, h2, as2, ad2);
    hipLaunchKernelGGL(k_agg2,  dim3(NNODES / 4), dim3(256), 0, stream, cnt, csr, h2, as2, ad2, b2, out);
}

// Round 9
// 208.304 us; speedup vs baseline: 1.0758x; 1.0016x over previous
//
#include <hip/hip_runtime.h>
#include <hip/hip_bf16.h>

#define NNODES 50000
#define NEDGES 800000
#define NFEATS 256
#define NHID 16
#define HEADS 8
#define NCLS 16
#define NEG_SLOPE 0.2f
#define TOTE (NEDGES + NNODES)
#define RSTRIDE 64      // fixed CSR row stride; P(deg+1 > 64) ~ 1e-20 for Poisson(16)
#define NBUCK 196       // buckets of 256 nodes: bucket = dst >> 8
#define NPB 256
#define BCAP 4864       // mean 4337, sigma ~66 -> +8 sigma
#define S1_EPT 16       // edges per thread in k_bin
#define BIN_BLOCKS ((TOTE + 4095) / 4096)   // 208
#define GSTRIDE 16      // gcnt padding: 1 counter per 64B line (cross-XCD atomic contention)
#define GEMM1_BLOCKS ((NNODES + 127) / 128) // 391

typedef __attribute__((ext_vector_type(8))) short short8;
typedef __attribute__((ext_vector_type(4))) float floatx4;

static __device__ __forceinline__ short f2bf(float f) {
    __hip_bfloat16 b = __float2bfloat16(f);
    return *reinterpret_cast<short*>(&b);
}

#define AS1 __attribute__((address_space(1)))
#define AS3 __attribute__((address_space(3)))

static __device__ __forceinline__ void ld_lds16(const void* g, void* l) {
#if __has_builtin(__builtin_amdgcn_global_load_lds)
    __builtin_amdgcn_global_load_lds((const AS1 void*)g, (AS3 void*)l, 16, 0, 0);
#endif
}

// ---------------- phase A: bin edges by dst>>8 (+ fused W1 pre-swizzle) --------

__global__ __launch_bounds__(256) void k_bin(const int* __restrict__ ei,
                                             int* __restrict__ gcnt, int* __restrict__ barr,
                                             const float* __restrict__ W,
                                             const float* __restrict__ a_s,
                                             const float* __restrict__ a_d,
                                             short* __restrict__ Wsw) {
    int tid = threadIdx.x;
    if (blockIdx.x >= BIN_BLOCKS) {
        int t = (blockIdx.x - BIN_BLOCKS) * 256 + tid;   // 4608 threads
        if (t >= 4608) return;
        short8 b;
        if (t < 4096) {
            int kc = t >> 9, nt = (t >> 6) & 7, lane = t & 63;
            int quad = lane >> 4, lo = lane & 15;
#pragma unroll
            for (int j = 0; j < 8; j++)
                b[j] = f2bf(W[(size_t)(kc * 32 + quad * 8 + j) * 128 + nt * 16 + lo]);
        } else {
            int t2 = t - 4096;
            int kc = t2 >> 6, lane = t2 & 63;
            int quad = lane >> 4, lo = lane & 15;
            int h = lo & 7;
            const float* av = (lo < 8) ? (a_s + h * 16) : (a_d + h * 16);
#pragma unroll
            for (int j = 0; j < 8; j++) {
                int k = kc * 32 + quad * 8 + j;
                float acc = 0.f;
#pragma unroll
                for (int c = 0; c < 16; c++) acc += W[(size_t)k * 128 + h * 16 + c] * av[c];
                b[j] = f2bf(acc);
            }
        }
        *(short8*)(Wsw + (size_t)t * 8) = b;
        return;
    }

    __shared__ int lcnt[NBUCK], lbase[NBUCK];
    if (tid < NBUCK) lcnt[tid] = 0;
    __syncthreads();
    int e0 = blockIdx.x * (256 * S1_EPT) + tid;
    int s[S1_EPT], d[S1_EPT], rk[S1_EPT];
#pragma unroll
    for (int k = 0; k < S1_EPT; k++) {
        int e = e0 + k * 256;
        bool v = e < TOTE;
        int ss = 0, dd = 0;
        if (v) {
            if (e < NEDGES) { ss = ei[e]; dd = ei[NEDGES + e]; }
            else            { ss = e - NEDGES; dd = ss; }
        }
        s[k] = ss; d[k] = dd;
        rk[k] = v ? atomicAdd(&lcnt[dd >> 8], 1) : -1;
    }
    __syncthreads();
    if (tid < NBUCK) lbase[tid] = lcnt[tid] ? atomicAdd(&gcnt[tid * GSTRIDE], lcnt[tid]) : 0;
    __syncthreads();
#pragma unroll
    for (int k = 0; k < S1_EPT; k++) {
        if (rk[k] >= 0) {
            int b = d[k] >> 8;
            int pos = lbase[b] + rk[k];
            if (pos < BCAP)
                barr[(size_t)b * BCAP + pos] = ((d[k] & 255) << 16) | s[k];
        }
    }
}

// ---------------- fused phase B: CSR build (blocks < NBUCK) + L1 GEMM ----------

__global__ __launch_bounds__(256) void k_mid(const int* __restrict__ gcnt,
                                             const int* __restrict__ barr,
                                             int* __restrict__ cnt, unsigned short* __restrict__ csr,
                                             const float* __restrict__ x,
                                             const short* __restrict__ Wsw,
                                             __hip_bfloat16* __restrict__ h1,
                                             float* __restrict__ as1, float* __restrict__ ad1) {
    __shared__ short smem[32768];   // 64 KB, shared by both paths
    int tid = threadIdx.x;

    if (blockIdx.x < NBUCK) {
        // ---- CSR path ----
        int* lcnt = (int*)smem;                         // 256 ints = 1 KB
        unsigned short* lcsr = (unsigned short*)smem + 512;  // 256*65 ushorts
        int b = blockIdx.x;
        lcnt[tid] = 0;
        __syncthreads();
        int n = min(gcnt[b * GSTRIDE], BCAP);
        int nodeBase = b << 8;
        for (int i = tid; i < n; i += 256) {
            int e = barr[(size_t)b * BCAP + i];
            int ln = e >> 16;
            int r = atomicAdd(&lcnt[ln], 1);
            if (r < RSTRIDE) lcsr[ln * 65 + r] = (unsigned short)(e & 0xFFFF);
        }
        __syncthreads();
        int node = nodeBase + tid;
        if (node < NNODES) cnt[node] = min(lcnt[tid], RSTRIDE);
        for (int i = tid; i < NPB * RSTRIDE; i += 256) {
            int ln = i >> 6;
            int nn = nodeBase + ln;
            if (nn < NNODES && (i & 63) < min(lcnt[ln], RSTRIDE))
                csr[(size_t)nodeBase * RSTRIDE + i] = lcsr[ln * 65 + (i & 63)];
        }
        return;
    }

    // ---- GEMM1 path ----
    short* bsw = smem;
    int bid  = blockIdx.x - NBUCK;
    int wave = tid >> 6;
    int lane = tid & 63;
    int quad = lane >> 4;
    int lo   = lane & 15;

#if __has_builtin(__builtin_amdgcn_global_load_lds)
    {
        const char* gsrc = (const char*)Wsw + (size_t)wave * 1024 + (size_t)lane * 16;
        char* ldst = (char*)bsw + wave * 1024;
#pragma unroll
        for (int it = 0; it < 16; it++)
            ld_lds16(gsrc + it * 4096, ldst + it * 4096);
    }
#else
    {
        const uint4* g4 = (const uint4*)Wsw;
        uint4* l4 = (uint4*)bsw;
#pragma unroll
        for (int it = 0; it < 16; it++) l4[it * 256 + tid] = g4[it * 256 + tid];
    }
#endif
    short8 wafr[8];
#pragma unroll
    for (int kc = 0; kc < 8; kc++)
        wafr[kc] = *(const short8*)(Wsw + (size_t)(4096 + kc * 64 + lane) * 8);
    __syncthreads();

    int rowBase = bid * 128 + wave * 32;
    const float* xa[2];
#pragma unroll
    for (int mt = 0; mt < 2; mt++) {
        int row = rowBase + mt * 16 + lo;
        row = (row < NNODES) ? row : (NNODES - 1);
        xa[mt] = x + (size_t)row * 256 + quad * 8;
    }

    floatx4 acc[2][8], accA[2];
#pragma unroll
    for (int mt = 0; mt < 2; mt++) {
        accA[mt] = (floatx4){0.f, 0.f, 0.f, 0.f};
#pragma unroll
        for (int nt = 0; nt < 8; nt++) acc[mt][nt] = (floatx4){0.f, 0.f, 0.f, 0.f};
    }

    float4 a0[2], a1[2];
#pragma unroll
    for (int mt = 0; mt < 2; mt++) {
        a0[mt] = *(const float4*)(xa[mt]);
        a1[mt] = *(const float4*)(xa[mt] + 4);
    }

    for (int kc = 0; kc < 8; kc++) {
        float4 n0[2], n1[2];
        if (kc < 7) {
#pragma unroll
            for (int mt = 0; mt < 2; mt++) {
                n0[mt] = *(const float4*)(xa[mt] + (kc + 1) * 32);
                n1[mt] = *(const float4*)(xa[mt] + (kc + 1) * 32 + 4);
            }
        }
        short8 afr[2];
#pragma unroll
        for (int mt = 0; mt < 2; mt++) {
            union { short8 s; __hip_bfloat162 h[4]; } u;
            u.h[0] = __float22bfloat162_rn(make_float2(a0[mt].x, a0[mt].y));
            u.h[1] = __float22bfloat162_rn(make_float2(a0[mt].z, a0[mt].w));
            u.h[2] = __float22bfloat162_rn(make_float2(a1[mt].x, a1[mt].y));
            u.h[3] = __float22bfloat162_rn(make_float2(a1[mt].z, a1[mt].w));
            afr[mt] = u.s;
        }
#pragma unroll
        for (int nt = 0; nt < 8; nt++) {
            short8 bfr = *(const short8*)&bsw[((kc * 8 + nt) * 64 + lane) * 8];
            acc[0][nt] = __builtin_amdgcn_mfma_f32_16x16x32_bf16(afr[0], bfr, acc[0][nt], 0, 0, 0);
            acc[1][nt] = __builtin_amdgcn_mfma_f32_16x16x32_bf16(afr[1], bfr, acc[1][nt], 0, 0, 0);
        }
        accA[0] = __builtin_amdgcn_mfma_f32_16x16x32_bf16(afr[0], wafr[kc], accA[0], 0, 0, 0);
        accA[1] = __builtin_amdgcn_mfma_f32_16x16x32_bf16(afr[1], wafr[kc], accA[1], 0, 0, 0);
#pragma unroll
        for (int mt = 0; mt < 2; mt++) { a0[mt] = n0[mt]; a1[mt] = n1[mt]; }
    }

#pragma unroll
    for (int mt = 0; mt < 2; mt++)
#pragma unroll
        for (int nt = 0; nt < 8; nt++)
#pragma unroll
            for (int reg = 0; reg < 4; reg++) {
                int row = rowBase + mt * 16 + quad * 4 + reg;
                int col = nt * 16 + lo;
                if (row < NNODES)
                    h1[(size_t)row * 128 + col] = __float2bfloat16(acc[mt][nt][reg]);
            }
#pragma unroll
    for (int mt = 0; mt < 2; mt++)
#pragma unroll
        for (int reg = 0; reg < 4; reg++) {
            int row = rowBase + mt * 16 + quad * 4 + reg;
            if (row < NNODES) {
                float v = accA[mt][reg];
                if (lo < 8) as1[(size_t)row * 8 + lo] = v;
                else        ad1[(size_t)row * 8 + (lo - 8)] = v;
            }
        }
}

// ---------------- layer-1 softmax-aggregate + bias + ELU (bf16 out) ------------
// Round-17: REVERT to the R2-proven pure-gather form (42.7us measured). The
// fused epilogue cost ~20us across ALL variants (global/LDS/transposed, with
// 3.4M/11.2M/4.0M bank conflicts -- no correlation with time): the kernel is
// latency-bound (VALU 54%, occ 62% in every variant; time ~ per-wave op count),
// so a ~70-op serial epilogue tail in each of 50000 waves cannot hide. The
// same FLOPs run as a separate massively-parallel kernel cost ~5us wall.

__global__ __launch_bounds__(256) void k_agg1(const int* __restrict__ cnt,
                                              const unsigned short* __restrict__ csr,
                                              const __hip_bfloat16* __restrict__ h1,
                                              const float* __restrict__ as1, const float* __restrict__ ad1,
                                              const float* __restrict__ b1, __hip_bfloat16* __restrict__ h1act) {
    int node = blockIdx.x * 4 + (threadIdx.x >> 6);    // 1 node / wave; grid exact
    int lane = threadIdx.x & 63;
    int cl   = lane & 15;                              // channel-slice (8 ch)
    int slot = lane >> 4;                              // edge slot 0..3
    int head = cl >> 1;
    int deg  = min(cnt[node], RSTRIDE);                // wave-uniform
    float adst = ad1[node * 8 + head];
    int rowv = csr[node * RSTRIDE + lane];             // full row, one coalesced load

    float acc[8] = {0.f, 0.f, 0.f, 0.f, 0.f, 0.f, 0.f, 0.f};
    float s = 0.f;
    for (int i2 = 0; i2 < deg; i2 += 16) {             // 16 edges/trip, 4 per slot
        float p[4];
        union { short8 v; __hip_bfloat162 h[4]; } u[4];
#pragma unroll
        for (int t = 0; t < 4; t++) {
            int ii = i2 + slot + t * 4;
            int src = __shfl(rowv, ii & 63);
            p[t] = 0.f;
            u[t].v = (short8){0, 0, 0, 0, 0, 0, 0, 0};
            if (ii < deg) {
                u[t].v = *(const short8*)(h1 + (size_t)src * 128 + cl * 8);
                float e = as1[src * 8 + head] + adst;
                e = (e > 0.f) ? e : NEG_SLOPE * e;
                p[t] = __expf(e);
            }
        }
        s += (p[0] + p[1]) + (p[2] + p[3]);
#pragma unroll
        for (int t = 0; t < 4; t++)
#pragma unroll
            for (int q = 0; q < 4; q++) {
                float2 f = __bfloat1622float2(u[t].h[q]);
                acc[q * 2]     = fmaf(p[t], f.x, acc[q * 2]);
                acc[q * 2 + 1] = fmaf(p[t], f.y, acc[q * 2 + 1]);
            }
    }
    // cross-slot reduction (slots live in lane bits 4,5)
#pragma unroll
    for (int q = 0; q < 8; q++) {
        acc[q] += __shfl_xor(acc[q], 16);
        acc[q] += __shfl_xor(acc[q], 32);
    }
    s += __shfl_xor(s, 16);
    s += __shfl_xor(s, 32);
    if (slot == 0) {
        float is = 1.f / s;
        union { short8 v; short us[8]; } pk;
#pragma unroll
        for (int q = 0; q < 8; q++) {
            float v = acc[q] * is + b1[cl * 8 + q];
            v = (v > 0.f) ? v : (__expf(v) - 1.f);        // ELU
            pk.us[q] = f2bf(v);
        }
        *(short8*)(h1act + (size_t)node * 128 + cl * 8) = pk.v;
    }
}

// ---------------- lean layer-2 GEMM (f32) + fused alpha2 ------------------------
// Round-17: replaces the old 16-rows/block gemm2 (~17-20us wall incl. gap) and
// the fused epilogue. 64 nodes/block, 4 threads/node split by k-quarter:
// contiguous 64B h1act reads (no redundancy), W2 staged once in LDS and read
// with node-independent addresses (16-lane broadcast per instruction; only the
// benign 4-address kq aliasing), 2-step shfl reduce, h2/as2/ad2 fused.
// ~512 FMA + 128 LDS reads per thread, 782 blocks -> ~5-8 us.

__global__ __launch_bounds__(256) void k_gemm2f(const __hip_bfloat16* __restrict__ h1act,
                                                const float* __restrict__ W2,
                                                const float* __restrict__ a_s2,
                                                const float* __restrict__ a_d2,
                                                float* __restrict__ h2,
                                                float* __restrict__ as2, float* __restrict__ ad2) {
    __shared__ float w2s[2048];                        // W2 [128][16] row-major
    int tid = threadIdx.x;
    for (int i = tid; i < 2048; i += 256) w2s[i] = W2[i];
    __syncthreads();

    int node = blockIdx.x * 64 + (tid >> 2);
    int kq   = tid & 3;                                // k-quarter 0..3
    bool valid = node < NNODES;
    int nn = valid ? node : NNODES - 1;

    // load this thread's 32-k slice of the h1act row (64B contiguous)
    float hv[32];
    const short8* hp = (const short8*)(h1act + (size_t)nn * 128 + kq * 32);
#pragma unroll
    for (int b = 0; b < 4; b++) {
        union { short8 v; __hip_bfloat162 h[4]; } u;
        u.v = hp[b];
#pragma unroll
        for (int q = 0; q < 4; q++) {
            float2 f = __bfloat1622float2(u.h[q]);
            hv[b * 8 + q * 2]     = f.x;
            hv[b * 8 + q * 2 + 1] = f.y;
        }
    }

    float part[16];
#pragma unroll
    for (int c = 0; c < 16; c++) part[c] = 0.f;
#pragma unroll
    for (int j = 0; j < 32; j++) {
        int k = kq * 32 + j;
        float hvj = hv[j];
        const float4* wr = (const float4*)(&w2s[k * 16]);
#pragma unroll
        for (int cb = 0; cb < 4; cb++) {
            float4 w4 = wr[cb];
            part[cb * 4 + 0] = fmaf(hvj, w4.x, part[cb * 4 + 0]);
            part[cb * 4 + 1] = fmaf(hvj, w4.y, part[cb * 4 + 1]);
            part[cb * 4 + 2] = fmaf(hvj, w4.z, part[cb * 4 + 2]);
            part[cb * 4 + 3] = fmaf(hvj, w4.w, part[cb * 4 + 3]);
        }
    }
    // reduce over the 4 kq threads (lane bits 0,1)
#pragma unroll
    for (int c = 0; c < 16; c++) {
        part[c] += __shfl_xor(part[c], 1);
        part[c] += __shfl_xor(part[c], 2);
    }
    if (valid && kq == 0) {
        float4* hp2 = (float4*)(h2 + (size_t)node * 16);
        hp2[0] = make_float4(part[0],  part[1],  part[2],  part[3]);
        hp2[1] = make_float4(part[4],  part[5],  part[6],  part[7]);
        hp2[2] = make_float4(part[8],  part[9],  part[10], part[11]);
        hp2[3] = make_float4(part[12], part[13], part[14], part[15]);
    }
    if (valid && kq == 1) {
        float sv = 0.f;
#pragma unroll
        for (int c = 0; c < 16; c++) sv = fmaf(part[c], a_s2[c], sv);
        as2[node] = sv;
    }
    if (valid && kq == 2) {
        float dv = 0.f;
#pragma unroll
        for (int c = 0; c < 16; c++) dv = fmaf(part[c], a_d2[c], dv);
        ad2[node] = dv;
    }
}

// ---------------- layer-2 softmax-aggregate + bias ------------------------------

__global__ __launch_bounds__(256) void k_agg2(const int* __restrict__ cnt,
                                              const unsigned short* __restrict__ csr,
                                              const float* __restrict__ h2, const float* __restrict__ as2,
                                              const float* __restrict__ ad2, const float* __restrict__ b2,
                                              float* __restrict__ out) {
    int node = blockIdx.x * 4 + (threadIdx.x >> 6);
    int lane = threadIdx.x & 63;
    int c4   = lane & 3;                               // channel quarter (4 floats)
    int slot = lane >> 2;                              // edge slot 0..15
    int deg  = min(cnt[node], RSTRIDE);                // wave-uniform
    float adst = ad2[node];
    int rowv = csr[node * RSTRIDE + lane];

    float4 acc = make_float4(0.f, 0.f, 0.f, 0.f);
    float s = 0.f;
    for (int i2 = 0; i2 < deg; i2 += 32) {             // 32 edges/trip, 2 per slot
        int ia = i2 + slot;
        int ib = ia + 16;
        int sa = __shfl(rowv, ia & 63);
        int sb = __shfl(rowv, ib & 63);
        float p0 = 0.f, p1 = 0.f;
        float4 r0 = make_float4(0.f, 0.f, 0.f, 0.f);
        float4 r1 = make_float4(0.f, 0.f, 0.f, 0.f);
        if (ia < deg) {
            r0 = *(const float4*)(h2 + (size_t)sa * 16 + c4 * 4);
            float e = as2[sa] + adst;
            e = (e > 0.f) ? e : NEG_SLOPE * e;
            p0 = __expf(e);
        }
        if (ib < deg) {
            r1 = *(const float4*)(h2 + (size_t)sb * 16 + c4 * 4);
            float e = as2[sb] + adst;
            e = (e > 0.f) ? e : NEG_SLOPE * e;
            p1 = __expf(e);
        }
        s += p0 + p1;
        acc.x = fmaf(p0, r0.x, fmaf(p1, r1.x, acc.x));
        acc.y = fmaf(p0, r0.y, fmaf(p1, r1.y, acc.y));
        acc.z = fmaf(p0, r0.z, fmaf(p1, r1.z, acc.z));
        acc.w = fmaf(p0, r0.w, fmaf(p1, r1.w, acc.w));
    }
#pragma unroll
    for (int o = 4; o <= 32; o <<= 1) {                // reduce over 16 slots
        acc.x += __shfl_xor(acc.x, o);
        acc.y += __shfl_xor(acc.y, o);
        acc.z += __shfl_xor(acc.z, o);
        acc.w += __shfl_xor(acc.w, o);
        s += __shfl_xor(s, o);
    }
    if (slot == 0) {
        float is = 1.f / s;
        float4 o4;
        o4.x = acc.x * is + b2[c4 * 4 + 0];
        o4.y = acc.y * is + b2[c4 * 4 + 1];
        o4.z = acc.z * is + b2[c4 * 4 + 2];
        o4.w = acc.w * is + b2[c4 * 4 + 3];
        *(float4*)(out + (size_t)node * 16 + c4 * 4) = o4;
    }
}

// ---------------- launch ----------------

extern "C" void kernel_launch(void* const* d_in, const int* in_sizes, int n_in,
                              void* d_out, int out_size, void* d_ws, size_t ws_size,
                              hipStream_t stream) {
    const float* x    = (const float*)d_in[0];
    const int*   ei   = (const int*)d_in[1];
    const float* W1   = (const float*)d_in[2];
    const float* a_s1 = (const float*)d_in[3];
    const float* a_d1 = (const float*)d_in[4];
    const float* b1   = (const float*)d_in[5];
    const float* W2   = (const float*)d_in[6];
    const float* a_s2 = (const float*)d_in[7];
    const float* a_d2 = (const float*)d_in[8];
    const float* b2   = (const float*)d_in[9];
    float* out = (float*)d_out;

    char* p = (char*)d_ws;
    auto alloc = [&](size_t bytes) -> char* {
        char* q = p;
        p += (bytes + 255) & ~(size_t)255;
        return q;
    };
    int*  gcnt = (int*)alloc((size_t)NBUCK * GSTRIDE * 4);        // 12.5 KB, padded
    int*  barr = (int*)alloc((size_t)NBUCK * BCAP * 4);           // 3.8 MB, dead after k_mid
    int*  cnt  = (int*)alloc((size_t)NNODES * 4);
    unsigned short* csr = (unsigned short*)alloc((size_t)NNODES * RSTRIDE * 2);  // 6.4 MB (ushort)
    short* Wsw = (short*)alloc((size_t)36864 * 2);                // 8 B-tiles + Wa tile
    __hip_bfloat16* h1 = (__hip_bfloat16*)alloc((size_t)NNODES * 128 * 2);
    float* as1 = (float*)alloc((size_t)NNODES * 8 * 4);
    float* ad1 = (float*)alloc((size_t)NNODES * 8 * 4);
    __hip_bfloat16* h1act = (__hip_bfloat16*)alloc((size_t)NNODES * 128 * 2);
    float* h2  = (float*)alloc((size_t)NNODES * 16 * 4);
    // aliases (regions dead by the time these are written):
    float* as2 = (float*)barr;           // over barr (dead after k_mid)
    float* ad2 = (float*)barr + NNODES;

    hipMemsetAsync(gcnt, 0, (size_t)NBUCK * GSTRIDE * 4, stream);
    hipLaunchKernelGGL(k_bin,    dim3(BIN_BLOCKS + 18), dim3(256), 0, stream,
                       ei, gcnt, barr, W1, a_s1, a_d1, Wsw);
    hipLaunchKernelGGL(k_mid,    dim3(NBUCK + GEMM1_BLOCKS), dim3(256), 0, stream,
                       gcnt, barr, cnt, csr, x, Wsw, h1, as1, ad1);
    hipLaunchKernelGGL(k_agg1,   dim3(NNODES / 4), dim3(256), 0, stream,
                       cnt, csr, h1, as1, ad1, b1, h1act);
    hipLaunchKernelGGL(k_gemm2f, dim3((NNODES + 63) / 64), dim3(256), 0, stream,
                       h1act, W2, a_s2, a_d2, h2, as2, ad2);
    hipLaunchKernelGGL(k_agg2,   dim3(NNODES / 4), dim3(256), 0, stream, cnt, csr, h2, as2, ad2, b2, out);
}

// Round 11
// 191.491 us; speedup vs baseline: 1.1702x; 1.0878x over previous
//
#include <hip/hip_runtime.h>
#include <hip/hip_bf16.h>

#define NNODES 50000
#define NEDGES 800000
#define NFEATS 256
#define NHID 16
#define HEADS 8
#define NCLS 16
#define NEG_SLOPE 0.2f
#define TOTE (NEDGES + NNODES)
#define RSTRIDE 64      // fixed CSR row stride; P(deg+1 > 64) ~ 1e-20 for Poisson(16)
#define NBUCK 196       // buckets of 256 nodes: bucket = dst >> 8
#define NPB 256
#define BCAP 4864       // mean 4337, sigma ~66 -> +8 sigma
#define S1_EPT 16       // edges per thread in k_bin
#define BIN_BLOCKS ((TOTE + 4095) / 4096)   // 208
#define GSTRIDE 16      // gcnt padding: 1 counter per 64B line (cross-XCD atomic contention)
#define GEMM1_BLOCKS ((NNODES + 127) / 128) // 391

typedef __attribute__((ext_vector_type(8))) short short8;
typedef __attribute__((ext_vector_type(4))) float floatx4;

static __device__ __forceinline__ short f2bf(float f) {
    __hip_bfloat16 b = __float2bfloat16(f);
    return *reinterpret_cast<short*>(&b);
}

#define AS1 __attribute__((address_space(1)))
#define AS3 __attribute__((address_space(3)))

static __device__ __forceinline__ void ld_lds16(const void* g, void* l) {
#if __has_builtin(__builtin_amdgcn_global_load_lds)
    __builtin_amdgcn_global_load_lds((const AS1 void*)g, (AS3 void*)l, 16, 0, 0);
#endif
}

// ---------------- phase A: bin edges by dst>>8 (+ fused W1 pre-swizzle) --------

__global__ __launch_bounds__(256) void k_bin(const int* __restrict__ ei,
                                             int* __restrict__ gcnt, int* __restrict__ barr,
                                             const float* __restrict__ W,
                                             const float* __restrict__ a_s,
                                             const float* __restrict__ a_d,
                                             short* __restrict__ Wsw) {
    int tid = threadIdx.x;
    if (blockIdx.x >= BIN_BLOCKS) {
        int t = (blockIdx.x - BIN_BLOCKS) * 256 + tid;   // 4608 threads
        if (t >= 4608) return;
        short8 b;
        if (t < 4096) {
            int kc = t >> 9, nt = (t >> 6) & 7, lane = t & 63;
            int quad = lane >> 4, lo = lane & 15;
#pragma unroll
            for (int j = 0; j < 8; j++)
                b[j] = f2bf(W[(size_t)(kc * 32 + quad * 8 + j) * 128 + nt * 16 + lo]);
        } else {
            int t2 = t - 4096;
            int kc = t2 >> 6, lane = t2 & 63;
            int quad = lane >> 4, lo = lane & 15;
            int h = lo & 7;
            const float* av = (lo < 8) ? (a_s + h * 16) : (a_d + h * 16);
#pragma unroll
            for (int j = 0; j < 8; j++) {
                int k = kc * 32 + quad * 8 + j;
                float acc = 0.f;
#pragma unroll
                for (int c = 0; c < 16; c++) acc += W[(size_t)k * 128 + h * 16 + c] * av[c];
                b[j] = f2bf(acc);
            }
        }
        *(short8*)(Wsw + (size_t)t * 8) = b;
        return;
    }

    __shared__ int lcnt[NBUCK], lbase[NBUCK];
    if (tid < NBUCK) lcnt[tid] = 0;
    __syncthreads();
    int e0 = blockIdx.x * (256 * S1_EPT) + tid;
    int s[S1_EPT], d[S1_EPT], rk[S1_EPT];
#pragma unroll
    for (int k = 0; k < S1_EPT; k++) {
        int e = e0 + k * 256;
        bool v = e < TOTE;
        int ss = 0, dd = 0;
        if (v) {
            if (e < NEDGES) { ss = ei[e]; dd = ei[NEDGES + e]; }
            else            { ss = e - NEDGES; dd = ss; }
        }
        s[k] = ss; d[k] = dd;
        rk[k] = v ? atomicAdd(&lcnt[dd >> 8], 1) : -1;
    }
    __syncthreads();
    if (tid < NBUCK) lbase[tid] = lcnt[tid] ? atomicAdd(&gcnt[tid * GSTRIDE], lcnt[tid]) : 0;
    __syncthreads();
#pragma unroll
    for (int k = 0; k < S1_EPT; k++) {
        if (rk[k] >= 0) {
            int b = d[k] >> 8;
            int pos = lbase[b] + rk[k];
            if (pos < BCAP)
                barr[(size_t)b * BCAP + pos] = ((d[k] & 255) << 16) | s[k];
        }
    }
}

// ---------------- fused phase B: CSR build (blocks < NBUCK) + L1 GEMM ----------

__global__ __launch_bounds__(256) void k_mid(const int* __restrict__ gcnt,
                                             const int* __restrict__ barr,
                                             int* __restrict__ cnt, unsigned short* __restrict__ csr,
                                             const float* __restrict__ x,
                                             const short* __restrict__ Wsw,
                                             __hip_bfloat16* __restrict__ h1,
                                             float* __restrict__ as1, float* __restrict__ ad1) {
    __shared__ short smem[32768];   // 64 KB, shared by both paths
    int tid = threadIdx.x;

    if (blockIdx.x < NBUCK) {
        // ---- CSR path ----
        int* lcnt = (int*)smem;                         // 256 ints = 1 KB
        unsigned short* lcsr = (unsigned short*)smem + 512;  // 256*65 ushorts
        int b = blockIdx.x;
        lcnt[tid] = 0;
        __syncthreads();
        int n = min(gcnt[b * GSTRIDE], BCAP);
        int nodeBase = b << 8;
        for (int i = tid; i < n; i += 256) {
            int e = barr[(size_t)b * BCAP + i];
            int ln = e >> 16;
            int r = atomicAdd(&lcnt[ln], 1);
            if (r < RSTRIDE) lcsr[ln * 65 + r] = (unsigned short)(e & 0xFFFF);
        }
        __syncthreads();
        int node = nodeBase + tid;
        if (node < NNODES) cnt[node] = min(lcnt[tid], RSTRIDE);
        for (int i = tid; i < NPB * RSTRIDE; i += 256) {
            int ln = i >> 6;
            int nn = nodeBase + ln;
            if (nn < NNODES && (i & 63) < min(lcnt[ln], RSTRIDE))
                csr[(size_t)nodeBase * RSTRIDE + i] = lcsr[ln * 65 + (i & 63)];
        }
        return;
    }

    // ---- GEMM1 path ----
    short* bsw = smem;
    int bid  = blockIdx.x - NBUCK;
    int wave = tid >> 6;
    int lane = tid & 63;
    int quad = lane >> 4;
    int lo   = lane & 15;

#if __has_builtin(__builtin_amdgcn_global_load_lds)
    {
        const char* gsrc = (const char*)Wsw + (size_t)wave * 1024 + (size_t)lane * 16;
        char* ldst = (char*)bsw + wave * 1024;
#pragma unroll
        for (int it = 0; it < 16; it++)
            ld_lds16(gsrc + it * 4096, ldst + it * 4096);
    }
#else
    {
        const uint4* g4 = (const uint4*)Wsw;
        uint4* l4 = (uint4*)bsw;
#pragma unroll
        for (int it = 0; it < 16; it++) l4[it * 256 + tid] = g4[it * 256 + tid];
    }
#endif
    short8 wafr[8];
#pragma unroll
    for (int kc = 0; kc < 8; kc++)
        wafr[kc] = *(const short8*)(Wsw + (size_t)(4096 + kc * 64 + lane) * 8);
    __syncthreads();

    int rowBase = bid * 128 + wave * 32;
    const float* xa[2];
#pragma unroll
    for (int mt = 0; mt < 2; mt++) {
        int row = rowBase + mt * 16 + lo;
        row = (row < NNODES) ? row : (NNODES - 1);
        xa[mt] = x + (size_t)row * 256 + quad * 8;
    }

    floatx4 acc[2][8], accA[2];
#pragma unroll
    for (int mt = 0; mt < 2; mt++) {
        accA[mt] = (floatx4){0.f, 0.f, 0.f, 0.f};
#pragma unroll
        for (int nt = 0; nt < 8; nt++) acc[mt][nt] = (floatx4){0.f, 0.f, 0.f, 0.f};
    }

    float4 a0[2], a1[2];
#pragma unroll
    for (int mt = 0; mt < 2; mt++) {
        a0[mt] = *(const float4*)(xa[mt]);
        a1[mt] = *(const float4*)(xa[mt] + 4);
    }

    for (int kc = 0; kc < 8; kc++) {
        float4 n0[2], n1[2];
        if (kc < 7) {
#pragma unroll
            for (int mt = 0; mt < 2; mt++) {
                n0[mt] = *(const float4*)(xa[mt] + (kc + 1) * 32);
                n1[mt] = *(const float4*)(xa[mt] + (kc + 1) * 32 + 4);
            }
        }
        short8 afr[2];
#pragma unroll
        for (int mt = 0; mt < 2; mt++) {
            union { short8 s; __hip_bfloat162 h[4]; } u;
            u.h[0] = __float22bfloat162_rn(make_float2(a0[mt].x, a0[mt].y));
            u.h[1] = __float22bfloat162_rn(make_float2(a0[mt].z, a0[mt].w));
            u.h[2] = __float22bfloat162_rn(make_float2(a1[mt].x, a1[mt].y));
            u.h[3] = __float22bfloat162_rn(make_float2(a1[mt].z, a1[mt].w));
            afr[mt] = u.s;
        }
#pragma unroll
        for (int nt = 0; nt < 8; nt++) {
            short8 bfr = *(const short8*)&bsw[((kc * 8 + nt) * 64 + lane) * 8];
            acc[0][nt] = __builtin_amdgcn_mfma_f32_16x16x32_bf16(afr[0], bfr, acc[0][nt], 0, 0, 0);
            acc[1][nt] = __builtin_amdgcn_mfma_f32_16x16x32_bf16(afr[1], bfr, acc[1][nt], 0, 0, 0);
        }
        accA[0] = __builtin_amdgcn_mfma_f32_16x16x32_bf16(afr[0], wafr[kc], accA[0], 0, 0, 0);
        accA[1] = __builtin_amdgcn_mfma_f32_16x16x32_bf16(afr[1], wafr[kc], accA[1], 0, 0, 0);
#pragma unroll
        for (int mt = 0; mt < 2; mt++) { a0[mt] = n0[mt]; a1[mt] = n1[mt]; }
    }

#pragma unroll
    for (int mt = 0; mt < 2; mt++)
#pragma unroll
        for (int nt = 0; nt < 8; nt++)
#pragma unroll
            for (int reg = 0; reg < 4; reg++) {
                int row = rowBase + mt * 16 + quad * 4 + reg;
                int col = nt * 16 + lo;
                if (row < NNODES)
                    h1[(size_t)row * 128 + col] = __float2bfloat16(acc[mt][nt][reg]);
            }
#pragma unroll
    for (int mt = 0; mt < 2; mt++)
#pragma unroll
        for (int reg = 0; reg < 4; reg++) {
            int row = rowBase + mt * 16 + quad * 4 + reg;
            if (row < NNODES) {
                float v = accA[mt][reg];
                if (lo < 8) as1[(size_t)row * 8 + lo] = v;
                else        ad1[(size_t)row * 8 + (lo - 8)] = v;
            }
        }
}

// ---------------- fused layer-1 aggregate + ELU + layer-2 GEMM + alpha2 --------
// Round-18 (resubmit; R10 was an infra acquire failure, same as R7): amortized
// fusion. A separate L2-GEMM dispatch costs ~18-22us (R3 vs R2/R9 arithmetic)
// and a per-wave fused epilogue at 50k waves costs ~17-20us -- both FIXED
// per-wave/per-launch costs. Fix: R0's proven 4-node/wave gather (41.5us;
// max-deg coupling free, latency-bound) + epilogue amortized 4x (four nodes'
// softmax/ELU in PARALLEL lane groups; only 12.5k waves pay the tail).
// Layer-2 GEMM: lane (nd,cl) owns out[cl] of node nd, reads its node's 128-k
// v-row from wave-local LDS vbuf (register->LDS, same-wave RAW, in-order LDS
// pipe, NO barrier) and W2 from a [c][k] stride-132 tile. Banks: vbuf reads
// broadcast across cl / distinct quads across nd; w2t reads 2-way -> free.
// One __syncthreads total (w2t staging, before the gather).

__global__ __launch_bounds__(256) void k_aggA(const int* __restrict__ cnt,
                                              const unsigned short* __restrict__ csr,
                                              const __hip_bfloat16* __restrict__ h1,
                                              const float* __restrict__ as1, const float* __restrict__ ad1,
                                              const float* __restrict__ b1,
                                              const float* __restrict__ W2,
                                              const float* __restrict__ a_s2,
                                              const float* __restrict__ a_d2,
                                              float* __restrict__ h2,
                                              float* __restrict__ as2, float* __restrict__ ad2) {
    __shared__ float w2t[16 * 132];                    // W2 transposed [c][k], pad 132
    __shared__ float vbuf[4 * 4 * 132];                // [wave][node][k], pad 132
    int tid = threadIdx.x;
#pragma unroll
    for (int i = 0; i < 8; i++) {
        int e = i * 256 + tid;                         // e = k*16 + c (W2 row-major)
        w2t[(e & 15) * 132 + (e >> 4)] = W2[e];
    }
    __syncthreads();                                   // only barrier; before gather

    int wavid = tid >> 6;
    int lane  = tid & 63;
    int cl    = lane & 15;                             // channel-slice (8 ch)
    int nd    = lane >> 4;                             // node-in-wave 0..3
    int node  = (blockIdx.x * 4 + wavid) * 4 + nd;     // grid exact: 50000/16 = 3125
    int head  = cl >> 1;
    int deg   = min(cnt[node], RSTRIDE);
    float adst = ad1[node * 8 + head];
    int rs = node * RSTRIDE;
    int rowv[4];
#pragma unroll
    for (int r = 0; r < 4; r++) rowv[r] = csr[rs + cl + 16 * r];
    int md = deg;
    md = max(md, __shfl_xor(md, 16));
    md = max(md, __shfl_xor(md, 32));                  // max over 4 nodes (wave-uniform)

    float acc[8] = {0.f, 0.f, 0.f, 0.f, 0.f, 0.f, 0.f, 0.f};
    float s = 0.f;
#pragma unroll
    for (int r = 0; r < 4; r++) {
        int rbase = r << 4;
        if (rbase >= md) break;                        // wave-uniform
        int lim = min(16, md - rbase);
        for (int i2 = 0; i2 < lim; i2 += 4) {          // MLP = 4
            float p[4];
            union { short8 v; __hip_bfloat162 h[4]; } u[4];
#pragma unroll
            for (int t = 0; t < 4; t++) {
                int idx = rbase + i2 + t;              // wave-uniform
                int src = __shfl(rowv[r], (lane & 48) | ((i2 + t) & 15));
                p[t] = 0.f;
                u[t].v = (short8){0, 0, 0, 0, 0, 0, 0, 0};
                if (idx < deg) {                       // per-node predicate
                    u[t].v = *(const short8*)(h1 + (size_t)src * 128 + cl * 8);
                    float e = as1[src * 8 + head] + adst;
                    e = (e > 0.f) ? e : NEG_SLOPE * e;
                    p[t] = __expf(e);
                }
            }
            s += (p[0] + p[1]) + (p[2] + p[3]);
#pragma unroll
            for (int t = 0; t < 4; t++)
#pragma unroll
                for (int q = 0; q < 4; q++) {
                    float2 f = __bfloat1622float2(u[t].h[q]);
                    acc[q * 2]     = fmaf(p[t], f.x, acc[q * 2]);
                    acc[q * 2 + 1] = fmaf(p[t], f.y, acc[q * 2 + 1]);
                }
        }
    }
    // every lane saw all its node's edges: s and acc complete. No reduction.
    float is = 1.f / s;
    float v[8];
#pragma unroll
    for (int q = 0; q < 8; q++) {
        float t = acc[q] * is + b1[cl * 8 + q];
        v[q] = (t > 0.f) ? t : (__expf(t) - 1.f);      // ELU
    }
    // register -> wave-local vbuf (same-wave RAW; lgkmcnt-ordered, no barrier)
    float* vb = &vbuf[(wavid * 4 + nd) * 132 + cl * 8];
    *(float4*)vb       = make_float4(v[0], v[1], v[2], v[3]);
    *(float4*)(vb + 4) = make_float4(v[4], v[5], v[6], v[7]);

    // layer-2 GEMM: lane (nd,cl) -> out[cl] of node nd over all 128 k
    const float* vrow = &vbuf[(wavid * 4 + nd) * 132];
    const float* wrow = &w2t[cl * 132];
    float outp = 0.f;
#pragma unroll
    for (int j = 0; j < 128; j += 4) {
        float4 vv = *(const float4*)(vrow + j);
        float4 ww = *(const float4*)(wrow + j);
        outp = fmaf(vv.x, ww.x, outp);
        outp = fmaf(vv.y, ww.y, outp);
        outp = fmaf(vv.z, ww.z, outp);
        outp = fmaf(vv.w, ww.w, outp);
    }
    h2[(size_t)node * 16 + cl] = outp;                 // 16 lanes -> 64B/node coalesced

    float sv = outp * a_s2[cl];
    float dv = outp * a_d2[cl];
#pragma unroll
    for (int o = 1; o <= 8; o <<= 1) {                 // reduce over cl group
        sv += __shfl_xor(sv, o);
        dv += __shfl_xor(dv, o);
    }
    if (cl == 0) { as2[node] = sv; ad2[node] = dv; }
}

// ---------------- layer-2 softmax-aggregate + bias ------------------------------

__global__ __launch_bounds__(256) void k_agg2(const int* __restrict__ cnt,
                                              const unsigned short* __restrict__ csr,
                                              const float* __restrict__ h2, const float* __restrict__ as2,
                                              const float* __restrict__ ad2, const float* __restrict__ b2,
                                              float* __restrict__ out) {
    int node = blockIdx.x * 4 + (threadIdx.x >> 6);
    int lane = threadIdx.x & 63;
    int c4   = lane & 3;                               // channel quarter (4 floats)
    int slot = lane >> 2;                              // edge slot 0..15
    int deg  = min(cnt[node], RSTRIDE);                // wave-uniform
    float adst = ad2[node];
    int rowv = csr[node * RSTRIDE + lane];

    float4 acc = make_float4(0.f, 0.f, 0.f, 0.f);
    float s = 0.f;
    for (int i2 = 0; i2 < deg; i2 += 32) {             // 32 edges/trip, 2 per slot
        int ia = i2 + slot;
        int ib = ia + 16;
        int sa = __shfl(rowv, ia & 63);
        int sb = __shfl(rowv, ib & 63);
        float p0 = 0.f, p1 = 0.f;
        float4 r0 = make_float4(0.f, 0.f, 0.f, 0.f);
        float4 r1 = make_float4(0.f, 0.f, 0.f, 0.f);
        if (ia < deg) {
            r0 = *(const float4*)(h2 + (size_t)sa * 16 + c4 * 4);
            float e = as2[sa] + adst;
            e = (e > 0.f) ? e : NEG_SLOPE * e;
            p0 = __expf(e);
        }
        if (ib < deg) {
            r1 = *(const float4*)(h2 + (size_t)sb * 16 + c4 * 4);
            float e = as2[sb] + adst;
            e = (e > 0.f) ? e : NEG_SLOPE * e;
            p1 = __expf(e);
        }
        s += p0 + p1;
        acc.x = fmaf(p0, r0.x, fmaf(p1, r1.x, acc.x));
        acc.y = fmaf(p0, r0.y, fmaf(p1, r1.y, acc.y));
        acc.z = fmaf(p0, r0.z, fmaf(p1, r1.z, acc.z));
        acc.w = fmaf(p0, r0.w, fmaf(p1, r1.w, acc.w));
    }
#pragma unroll
    for (int o = 4; o <= 32; o <<= 1) {                // reduce over 16 slots
        acc.x += __shfl_xor(acc.x, o);
        acc.y += __shfl_xor(acc.y, o);
        acc.z += __shfl_xor(acc.z, o);
        acc.w += __shfl_xor(acc.w, o);
        s += __shfl_xor(s, o);
    }
    if (slot == 0) {
        float is = 1.f / s;
        float4 o4;
        o4.x = acc.x * is + b2[c4 * 4 + 0];
        o4.y = acc.y * is + b2[c4 * 4 + 1];
        o4.z = acc.z * is + b2[c4 * 4 + 2];
        o4.w = acc.w * is + b2[c4 * 4 + 3];
        *(float4*)(out + (size_t)node * 16 + c4 * 4) = o4;
    }
}

// ---------------- launch ----------------

extern "C" void kernel_launch(void* const* d_in, const int* in_sizes, int n_in,
                              void* d_out, int out_size, void* d_ws, size_t ws_size,
                              hipStream_t stream) {
    const float* x    = (const float*)d_in[0];
    const int*   ei   = (const int*)d_in[1];
    const float* W1   = (const float*)d_in[2];
    const float* a_s1 = (const float*)d_in[3];
    const float* a_d1 = (const float*)d_in[4];
    const float* b1   = (const float*)d_in[5];
    const float* W2   = (const float*)d_in[6];
    const float* a_s2 = (const float*)d_in[7];
    const float* a_d2 = (const float*)d_in[8];
    const float* b2   = (const float*)d_in[9];
    float* out = (float*)d_out;

    char* p = (char*)d_ws;
    auto alloc = [&](size_t bytes) -> char* {
        char* q = p;
        p += (bytes + 255) & ~(size_t)255;
        return q;
    };
    int*  gcnt = (int*)alloc((size_t)NBUCK * GSTRIDE * 4);        // 12.5 KB, padded
    int*  barr = (int*)alloc((size_t)NBUCK * BCAP * 4);           // 3.8 MB, dead after k_mid
    int*  cnt  = (int*)alloc((size_t)NNODES * 4);
    unsigned short* csr = (unsigned short*)alloc((size_t)NNODES * RSTRIDE * 2);  // 6.4 MB (ushort)
    short* Wsw = (short*)alloc((size_t)36864 * 2);                // 8 B-tiles + Wa tile
    __hip_bfloat16* h1 = (__hip_bfloat16*)alloc((size_t)NNODES * 128 * 2);
    float* as1 = (float*)alloc((size_t)NNODES * 8 * 4);
    float* ad1 = (float*)alloc((size_t)NNODES * 8 * 4);
    float* h2  = (float*)alloc((size_t)NNODES * 16 * 4);          // own region: as1/ad1 live
                                                                  // concurrently in k_aggA
    // aliases (regions dead by the time these are written):
    float* as2 = (float*)barr;           // over barr (dead after k_mid)
    float* ad2 = (float*)barr + NNODES;

    hipMemsetAsync(gcnt, 0, (size_t)NBUCK * GSTRIDE * 4, stream);
    hipLaunchKernelGGL(k_bin,  dim3(BIN_BLOCKS + 18), dim3(256), 0, stream,
                       ei, gcnt, barr, W1, a_s1, a_d1, Wsw);
    hipLaunchKernelGGL(k_mid,  dim3(NBUCK + GEMM1_BLOCKS), dim3(256), 0, stream,
                       gcnt, barr, cnt, csr, x, Wsw, h1, as1, ad1);
    hipLaunchKernelGGL(k_aggA, dim3(NNODES / 16), dim3(256), 0, stream,
                       cnt, csr, h1, as1, ad1, b1, W2, a_s2, a_d2, h2, as2, ad2);
    hipLaunchKernelGGL(k_agg2, dim3(NNODES / 4), dim3(256), 0, stream, cnt, csr, h2, as2, ad2, b2, out);
}

// Round 12
// 187.510 us; speedup vs baseline: 1.1951x; 1.0212x over previous
//
#include <hip/hip_runtime.h>
#include <hip/hip_bf16.h>

#define NNODES 50000
#define NEDGES 800000
#define NFEATS 256
#define NHID 16
#define HEADS 8
#define NCLS 16
#define NEG_SLOPE 0.2f
#define TOTE (NEDGES + NNODES)
#define RSTRIDE 64      // fixed CSR row stride; P(deg+1 > 64) ~ 1e-20 for Poisson(16)
#define NBUCK 196       // buckets of 256 nodes: bucket = dst >> 8
#define NPB 256
#define BCAP 4864       // mean 4337, sigma ~66 -> +8 sigma
#define S1_EPT 16       // edges per thread in k_bin
#define BIN_BLOCKS ((TOTE + 4095) / 4096)   // 208
#define GSTRIDE 16      // gcnt padding: 1 counter per 64B line (cross-XCD atomic contention)
#define GEMM1_BLOCKS ((NNODES + 127) / 128) // 391

typedef __attribute__((ext_vector_type(8))) short short8;
typedef __attribute__((ext_vector_type(4))) float floatx4;

static __device__ __forceinline__ short f2bf(float f) {
    __hip_bfloat16 b = __float2bfloat16(f);
    return *reinterpret_cast<short*>(&b);
}

#define AS1 __attribute__((address_space(1)))
#define AS3 __attribute__((address_space(3)))

static __device__ __forceinline__ void ld_lds16(const void* g, void* l) {
#if __has_builtin(__builtin_amdgcn_global_load_lds)
    __builtin_amdgcn_global_load_lds((const AS1 void*)g, (AS3 void*)l, 16, 0, 0);
#endif
}

// ---------------- phase A: bin edges by dst>>8 (+ fused W1 pre-swizzle) --------

__global__ __launch_bounds__(256) void k_bin(const int* __restrict__ ei,
                                             int* __restrict__ gcnt, int* __restrict__ barr,
                                             const float* __restrict__ W,
                                             const float* __restrict__ a_s,
                                             const float* __restrict__ a_d,
                                             short* __restrict__ Wsw) {
    int tid = threadIdx.x;
    if (blockIdx.x >= BIN_BLOCKS) {
        int t = (blockIdx.x - BIN_BLOCKS) * 256 + tid;   // 4608 threads
        if (t >= 4608) return;
        short8 b;
        if (t < 4096) {
            int kc = t >> 9, nt = (t >> 6) & 7, lane = t & 63;
            int quad = lane >> 4, lo = lane & 15;
#pragma unroll
            for (int j = 0; j < 8; j++)
                b[j] = f2bf(W[(size_t)(kc * 32 + quad * 8 + j) * 128 + nt * 16 + lo]);
        } else {
            int t2 = t - 4096;
            int kc = t2 >> 6, lane = t2 & 63;
            int quad = lane >> 4, lo = lane & 15;
            int h = lo & 7;
            const float* av = (lo < 8) ? (a_s + h * 16) : (a_d + h * 16);
#pragma unroll
            for (int j = 0; j < 8; j++) {
                int k = kc * 32 + quad * 8 + j;
                float acc = 0.f;
#pragma unroll
                for (int c = 0; c < 16; c++) acc += W[(size_t)k * 128 + h * 16 + c] * av[c];
                b[j] = f2bf(acc);
            }
        }
        *(short8*)(Wsw + (size_t)t * 8) = b;
        return;
    }

    __shared__ int lcnt[NBUCK], lbase[NBUCK];
    if (tid < NBUCK) lcnt[tid] = 0;
    __syncthreads();
    int e0 = blockIdx.x * (256 * S1_EPT) + tid;
    int s[S1_EPT], d[S1_EPT], rk[S1_EPT];
#pragma unroll
    for (int k = 0; k < S1_EPT; k++) {
        int e = e0 + k * 256;
        bool v = e < TOTE;
        int ss = 0, dd = 0;
        if (v) {
            if (e < NEDGES) { ss = ei[e]; dd = ei[NEDGES + e]; }
            else            { ss = e - NEDGES; dd = ss; }
        }
        s[k] = ss; d[k] = dd;
        rk[k] = v ? atomicAdd(&lcnt[dd >> 8], 1) : -1;
    }
    __syncthreads();
    if (tid < NBUCK) lbase[tid] = lcnt[tid] ? atomicAdd(&gcnt[tid * GSTRIDE], lcnt[tid]) : 0;
    __syncthreads();
#pragma unroll
    for (int k = 0; k < S1_EPT; k++) {
        if (rk[k] >= 0) {
            int b = d[k] >> 8;
            int pos = lbase[b] + rk[k];
            if (pos < BCAP)
                barr[(size_t)b * BCAP + pos] = ((d[k] & 255) << 16) | s[k];
        }
    }
}

// ---------------- fused phase B: CSR build (blocks < NBUCK) + L1 GEMM ----------

__global__ __launch_bounds__(256) void k_mid(const int* __restrict__ gcnt,
                                             const int* __restrict__ barr,
                                             int* __restrict__ cnt, unsigned short* __restrict__ csr,
                                             const float* __restrict__ x,
                                             const short* __restrict__ Wsw,
                                             __hip_bfloat16* __restrict__ h1,
                                             float* __restrict__ as1, float* __restrict__ ad1) {
    __shared__ short smem[32768];   // 64 KB, shared by both paths
    int tid = threadIdx.x;

    if (blockIdx.x < NBUCK) {
        // ---- CSR path ----
        int* lcnt = (int*)smem;                         // 256 ints = 1 KB
        unsigned short* lcsr = (unsigned short*)smem + 512;  // 256*65 ushorts
        int b = blockIdx.x;
        lcnt[tid] = 0;
        __syncthreads();
        int n = min(gcnt[b * GSTRIDE], BCAP);
        int nodeBase = b << 8;
        for (int i = tid; i < n; i += 256) {
            int e = barr[(size_t)b * BCAP + i];
            int ln = e >> 16;
            int r = atomicAdd(&lcnt[ln], 1);
            if (r < RSTRIDE) lcsr[ln * 65 + r] = (unsigned short)(e & 0xFFFF);
        }
        __syncthreads();
        int node = nodeBase + tid;
        if (node < NNODES) cnt[node] = min(lcnt[tid], RSTRIDE);
        for (int i = tid; i < NPB * RSTRIDE; i += 256) {
            int ln = i >> 6;
            int nn = nodeBase + ln;
            if (nn < NNODES && (i & 63) < min(lcnt[ln], RSTRIDE))
                csr[(size_t)nodeBase * RSTRIDE + i] = lcsr[ln * 65 + (i & 63)];
        }
        return;
    }

    // ---- GEMM1 path ----
    short* bsw = smem;
    int bid  = blockIdx.x - NBUCK;
    int wave = tid >> 6;
    int lane = tid & 63;
    int quad = lane >> 4;
    int lo   = lane & 15;

#if __has_builtin(__builtin_amdgcn_global_load_lds)
    {
        const char* gsrc = (const char*)Wsw + (size_t)wave * 1024 + (size_t)lane * 16;
        char* ldst = (char*)bsw + wave * 1024;
#pragma unroll
        for (int it = 0; it < 16; it++)
            ld_lds16(gsrc + it * 4096, ldst + it * 4096);
    }
#else
    {
        const uint4* g4 = (const uint4*)Wsw;
        uint4* l4 = (uint4*)bsw;
#pragma unroll
        for (int it = 0; it < 16; it++) l4[it * 256 + tid] = g4[it * 256 + tid];
    }
#endif
    short8 wafr[8];
#pragma unroll
    for (int kc = 0; kc < 8; kc++)
        wafr[kc] = *(const short8*)(Wsw + (size_t)(4096 + kc * 64 + lane) * 8);
    __syncthreads();

    int rowBase = bid * 128 + wave * 32;
    const float* xa[2];
#pragma unroll
    for (int mt = 0; mt < 2; mt++) {
        int row = rowBase + mt * 16 + lo;
        row = (row < NNODES) ? row : (NNODES - 1);
        xa[mt] = x + (size_t)row * 256 + quad * 8;
    }

    floatx4 acc[2][8], accA[2];
#pragma unroll
    for (int mt = 0; mt < 2; mt++) {
        accA[mt] = (floatx4){0.f, 0.f, 0.f, 0.f};
#pragma unroll
        for (int nt = 0; nt < 8; nt++) acc[mt][nt] = (floatx4){0.f, 0.f, 0.f, 0.f};
    }

    float4 a0[2], a1[2];
#pragma unroll
    for (int mt = 0; mt < 2; mt++) {
        a0[mt] = *(const float4*)(xa[mt]);
        a1[mt] = *(const float4*)(xa[mt] + 4);
    }

    for (int kc = 0; kc < 8; kc++) {
        float4 n0[2], n1[2];
        if (kc < 7) {
#pragma unroll
            for (int mt = 0; mt < 2; mt++) {
                n0[mt] = *(const float4*)(xa[mt] + (kc + 1) * 32);
                n1[mt] = *(const float4*)(xa[mt] + (kc + 1) * 32 + 4);
            }
        }
        short8 afr[2];
#pragma unroll
        for (int mt = 0; mt < 2; mt++) {
            union { short8 s; __hip_bfloat162 h[4]; } u;
            u.h[0] = __float22bfloat162_rn(make_float2(a0[mt].x, a0[mt].y));
            u.h[1] = __float22bfloat162_rn(make_float2(a0[mt].z, a0[mt].w));
            u.h[2] = __float22bfloat162_rn(make_float2(a1[mt].x, a1[mt].y));
            u.h[3] = __float22bfloat162_rn(make_float2(a1[mt].z, a1[mt].w));
            afr[mt] = u.s;
        }
#pragma unroll
        for (int nt = 0; nt < 8; nt++) {
            short8 bfr = *(const short8*)&bsw[((kc * 8 + nt) * 64 + lane) * 8];
            acc[0][nt] = __builtin_amdgcn_mfma_f32_16x16x32_bf16(afr[0], bfr, acc[0][nt], 0, 0, 0);
            acc[1][nt] = __builtin_amdgcn_mfma_f32_16x16x32_bf16(afr[1], bfr, acc[1][nt], 0, 0, 0);
        }
        accA[0] = __builtin_amdgcn_mfma_f32_16x16x32_bf16(afr[0], wafr[kc], accA[0], 0, 0, 0);
        accA[1] = __builtin_amdgcn_mfma_f32_16x16x32_bf16(afr[1], wafr[kc], accA[1], 0, 0, 0);
#pragma unroll
        for (int mt = 0; mt < 2; mt++) { a0[mt] = n0[mt]; a1[mt] = n1[mt]; }
    }

#pragma unroll
    for (int mt = 0; mt < 2; mt++)
#pragma unroll
        for (int nt = 0; nt < 8; nt++)
#pragma unroll
            for (int reg = 0; reg < 4; reg++) {
                int row = rowBase + mt * 16 + quad * 4 + reg;
                int col = nt * 16 + lo;
                if (row < NNODES)
                    h1[(size_t)row * 128 + col] = __float2bfloat16(acc[mt][nt][reg]);
            }
#pragma unroll
    for (int mt = 0; mt < 2; mt++)
#pragma unroll
        for (int reg = 0; reg < 4; reg++) {
            int row = rowBase + mt * 16 + quad * 4 + reg;
            if (row < NNODES) {
                float v = accA[mt][reg];
                if (lo < 8) as1[(size_t)row * 8 + lo] = v;
                else        ad1[(size_t)row * 8 + (lo - 8)] = v;
            }
        }
}

// ---------------- fused layer-1 aggregate + ELU + layer-2 GEMM + alpha2 --------
// Round-18 (measured 44.5us, R11): amortized fusion. 4-node/wave gather +
// epilogue in parallel lane groups; layer-2 GEMM from wave-local vbuf (no
// barrier) + stride-132 w2t tile. Validated: conflicts 400k, LDS 16.9KB,
// total absorbed L2-GEMM for ~3us over the pure gather.

__global__ __launch_bounds__(256) void k_aggA(const int* __restrict__ cnt,
                                              const unsigned short* __restrict__ csr,
                                              const __hip_bfloat16* __restrict__ h1,
                                              const float* __restrict__ as1, const float* __restrict__ ad1,
                                              const float* __restrict__ b1,
                                              const float* __restrict__ W2,
                                              const float* __restrict__ a_s2,
                                              const float* __restrict__ a_d2,
                                              float* __restrict__ h2,
                                              float* __restrict__ as2, float* __restrict__ ad2) {
    __shared__ float w2t[16 * 132];                    // W2 transposed [c][k], pad 132
    __shared__ float vbuf[4 * 4 * 132];                // [wave][node][k], pad 132
    int tid = threadIdx.x;
#pragma unroll
    for (int i = 0; i < 8; i++) {
        int e = i * 256 + tid;                         // e = k*16 + c (W2 row-major)
        w2t[(e & 15) * 132 + (e >> 4)] = W2[e];
    }
    __syncthreads();                                   // only barrier; before gather

    int wavid = tid >> 6;
    int lane  = tid & 63;
    int cl    = lane & 15;                             // channel-slice (8 ch)
    int nd    = lane >> 4;                             // node-in-wave 0..3
    int node  = (blockIdx.x * 4 + wavid) * 4 + nd;     // grid exact: 50000/16 = 3125
    int head  = cl >> 1;
    int deg   = min(cnt[node], RSTRIDE);
    float adst = ad1[node * 8 + head];
    int rs = node * RSTRIDE;
    int rowv[4];
#pragma unroll
    for (int r = 0; r < 4; r++) rowv[r] = csr[rs + cl + 16 * r];
    int md = deg;
    md = max(md, __shfl_xor(md, 16));
    md = max(md, __shfl_xor(md, 32));                  // max over 4 nodes (wave-uniform)

    float acc[8] = {0.f, 0.f, 0.f, 0.f, 0.f, 0.f, 0.f, 0.f};
    float s = 0.f;
#pragma unroll
    for (int r = 0; r < 4; r++) {
        int rbase = r << 4;
        if (rbase >= md) break;                        // wave-uniform
        int lim = min(16, md - rbase);
        for (int i2 = 0; i2 < lim; i2 += 4) {          // MLP = 4
            float p[4];
            union { short8 v; __hip_bfloat162 h[4]; } u[4];
#pragma unroll
            for (int t = 0; t < 4; t++) {
                int idx = rbase + i2 + t;              // wave-uniform
                int src = __shfl(rowv[r], (lane & 48) | ((i2 + t) & 15));
                p[t] = 0.f;
                u[t].v = (short8){0, 0, 0, 0, 0, 0, 0, 0};
                if (idx < deg) {                       // per-node predicate
                    u[t].v = *(const short8*)(h1 + (size_t)src * 128 + cl * 8);
                    float e = as1[src * 8 + head] + adst;
                    e = (e > 0.f) ? e : NEG_SLOPE * e;
                    p[t] = __expf(e);
                }
            }
            s += (p[0] + p[1]) + (p[2] + p[3]);
#pragma unroll
            for (int t = 0; t < 4; t++)
#pragma unroll
                for (int q = 0; q < 4; q++) {
                    float2 f = __bfloat1622float2(u[t].h[q]);
                    acc[q * 2]     = fmaf(p[t], f.x, acc[q * 2]);
                    acc[q * 2 + 1] = fmaf(p[t], f.y, acc[q * 2 + 1]);
                }
        }
    }
    // every lane saw all its node's edges: s and acc complete. No reduction.
    float is = 1.f / s;
    float v[8];
#pragma unroll
    for (int q = 0; q < 8; q++) {
        float t = acc[q] * is + b1[cl * 8 + q];
        v[q] = (t > 0.f) ? t : (__expf(t) - 1.f);      // ELU
    }
    // register -> wave-local vbuf (same-wave RAW; lgkmcnt-ordered, no barrier)
    float* vb = &vbuf[(wavid * 4 + nd) * 132 + cl * 8];
    *(float4*)vb       = make_float4(v[0], v[1], v[2], v[3]);
    *(float4*)(vb + 4) = make_float4(v[4], v[5], v[6], v[7]);

    // layer-2 GEMM: lane (nd,cl) -> out[cl] of node nd over all 128 k
    const float* vrow = &vbuf[(wavid * 4 + nd) * 132];
    const float* wrow = &w2t[cl * 132];
    float outp = 0.f;
#pragma unroll
    for (int j = 0; j < 128; j += 4) {
        float4 vv = *(const float4*)(vrow + j);
        float4 ww = *(const float4*)(wrow + j);
        outp = fmaf(vv.x, ww.x, outp);
        outp = fmaf(vv.y, ww.y, outp);
        outp = fmaf(vv.z, ww.z, outp);
        outp = fmaf(vv.w, ww.w, outp);
    }
    h2[(size_t)node * 16 + cl] = outp;                 // 16 lanes -> 64B/node coalesced

    float sv = outp * a_s2[cl];
    float dv = outp * a_d2[cl];
#pragma unroll
    for (int o = 1; o <= 8; o <<= 1) {                 // reduce over cl group
        sv += __shfl_xor(sv, o);
        dv += __shfl_xor(dv, o);
    }
    if (cl == 0) { as2[node] = sv; ad2[node] = dv; }
}

// ---------------- layer-2 softmax-aggregate + bias ------------------------------
// Round-19: amortized like aggA. Inferred ~40us at 50k waves; the h2 gather is
// only ~2us of L2-resident data movement, so ~95% is per-wave fixed cost
// (csr row, cnt/ad2 loads, 20-shfl tail, write). 4 nodes/wave: lanes =
// 4 nd x (4 slots x 4 ch). rowv[4] register row with UNROLLED r-loop +
// wave-uniform break (rule-#20-safe); MLP=2 per lane; slot-reduce = 2 shfl
// steps (bits 2,3); coalesced 64B/node write by slot-0 lanes. Waves 4x down,
// tail 4x amortized, per-node load count unchanged.

__global__ __launch_bounds__(256) void k_agg2(const int* __restrict__ cnt,
                                              const unsigned short* __restrict__ csr,
                                              const float* __restrict__ h2, const float* __restrict__ as2,
                                              const float* __restrict__ ad2, const float* __restrict__ b2,
                                              float* __restrict__ out) {
    int tid   = threadIdx.x;
    int wavid = tid >> 6;
    int lane  = tid & 63;
    int nd    = lane >> 4;                             // node-in-wave 0..3
    int sub   = lane & 15;
    int slot  = sub >> 2;                              // edge slot 0..3
    int c4    = sub & 3;                               // channel quarter (4 floats)
    int node  = (blockIdx.x * 4 + wavid) * 4 + nd;     // grid exact: 50000/16 = 3125
    int deg   = min(cnt[node], RSTRIDE);
    float adst = ad2[node];
    int rs = node * RSTRIDE;
    int rowv[4];
#pragma unroll
    for (int r = 0; r < 4; r++) rowv[r] = csr[rs + sub + 16 * r];
    int md = deg;
    md = max(md, __shfl_xor(md, 16));
    md = max(md, __shfl_xor(md, 32));                  // max over 4 nodes (wave-uniform)

    float4 acc = make_float4(0.f, 0.f, 0.f, 0.f);
    float s = 0.f;
#pragma unroll
    for (int r = 0; r < 4; r++) {
        int rbase = r << 4;
        if (rbase >= md) break;                        // wave-uniform
        int lim = min(16, md - rbase);
        for (int i2 = 0; i2 < lim; i2 += 8) {          // MLP = 2 (2 edges per slot)
            int ia = rbase + i2 + slot;
            int ib = ia + 4;
            int sa = __shfl(rowv[r], (lane & 48) | (i2 + slot));
            int sb = __shfl(rowv[r], (lane & 48) | (i2 + 4 + slot));
            float p0 = 0.f, p1 = 0.f;
            float4 r0 = make_float4(0.f, 0.f, 0.f, 0.f);
            float4 r1 = make_float4(0.f, 0.f, 0.f, 0.f);
            if (ia < deg) {
                r0 = *(const float4*)(h2 + (size_t)sa * 16 + c4 * 4);
                float e = as2[sa] + adst;
                e = (e > 0.f) ? e : NEG_SLOPE * e;
                p0 = __expf(e);
            }
            if (ib < deg) {
                r1 = *(const float4*)(h2 + (size_t)sb * 16 + c4 * 4);
                float e = as2[sb] + adst;
                e = (e > 0.f) ? e : NEG_SLOPE * e;
                p1 = __expf(e);
            }
            s += p0 + p1;
            acc.x = fmaf(p0, r0.x, fmaf(p1, r1.x, acc.x));
            acc.y = fmaf(p0, r0.y, fmaf(p1, r1.y, acc.y));
            acc.z = fmaf(p0, r0.z, fmaf(p1, r1.z, acc.z));
            acc.w = fmaf(p0, r0.w, fmaf(p1, r1.w, acc.w));
        }
    }
    // reduce over the 4 slots (lane bits 2,3)
#pragma unroll
    for (int o = 4; o <= 8; o <<= 1) {
        acc.x += __shfl_xor(acc.x, o);
        acc.y += __shfl_xor(acc.y, o);
        acc.z += __shfl_xor(acc.z, o);
        acc.w += __shfl_xor(acc.w, o);
        s += __shfl_xor(s, o);
    }
    if (slot == 0) {
        float is = 1.f / s;
        float4 o4;
        o4.x = acc.x * is + b2[c4 * 4 + 0];
        o4.y = acc.y * is + b2[c4 * 4 + 1];
        o4.z = acc.z * is + b2[c4 * 4 + 2];
        o4.w = acc.w * is + b2[c4 * 4 + 3];
        *(float4*)(out + (size_t)node * 16 + c4 * 4) = o4;   // 4 lanes x 16B, coalesced
    }
}

// ---------------- launch ----------------

extern "C" void kernel_launch(void* const* d_in, const int* in_sizes, int n_in,
                              void* d_out, int out_size, void* d_ws, size_t ws_size,
                              hipStream_t stream) {
    const float* x    = (const float*)d_in[0];
    const int*   ei   = (const int*)d_in[1];
    const float* W1   = (const float*)d_in[2];
    const float* a_s1 = (const float*)d_in[3];
    const float* a_d1 = (const float*)d_in[4];
    const float* b1   = (const float*)d_in[5];
    const float* W2   = (const float*)d_in[6];
    const float* a_s2 = (const float*)d_in[7];
    const float* a_d2 = (const float*)d_in[8];
    const float* b2   = (const float*)d_in[9];
    float* out = (float*)d_out;

    char* p = (char*)d_ws;
    auto alloc = [&](size_t bytes) -> char* {
        char* q = p;
        p += (bytes + 255) & ~(size_t)255;
        return q;
    };
    int*  gcnt = (int*)alloc((size_t)NBUCK * GSTRIDE * 4);        // 12.5 KB, padded
    int*  barr = (int*)alloc((size_t)NBUCK * BCAP * 4);           // 3.8 MB, dead after k_mid
    int*  cnt  = (int*)alloc((size_t)NNODES * 4);
    unsigned short* csr = (unsigned short*)alloc((size_t)NNODES * RSTRIDE * 2);  // 6.4 MB (ushort)
    short* Wsw = (short*)alloc((size_t)36864 * 2);                // 8 B-tiles + Wa tile
    __hip_bfloat16* h1 = (__hip_bfloat16*)alloc((size_t)NNODES * 128 * 2);
    float* as1 = (float*)alloc((size_t)NNODES * 8 * 4);
    float* ad1 = (float*)alloc((size_t)NNODES * 8 * 4);
    float* h2  = (float*)alloc((size_t)NNODES * 16 * 4);          // own region: as1/ad1 live
                                                                  // concurrently in k_aggA
    // aliases (regions dead by the time these are written):
    float* as2 = (float*)barr;           // over barr (dead after k_mid)
    float* ad2 = (float*)barr + NNODES;

    hipMemsetAsync(gcnt, 0, (size_t)NBUCK * GSTRIDE * 4, stream);
    hipLaunchKernelGGL(k_bin,  dim3(BIN_BLOCKS + 18), dim3(256), 0, stream,
                       ei, gcnt, barr, W1, a_s1, a_d1, Wsw);
    hipLaunchKernelGGL(k_mid,  dim3(NBUCK + GEMM1_BLOCKS), dim3(256), 0, stream,
                       gcnt, barr, cnt, csr, x, Wsw, h1, as1, ad1);
    hipLaunchKernelGGL(k_aggA, dim3(NNODES / 16), dim3(256), 0, stream,
                       cnt, csr, h1, as1, ad1, b1, W2, a_s2, a_d2, h2, as2, ad2);
    hipLaunchKernelGGL(k_agg2, dim3(NNODES / 16), dim3(256), 0, stream, cnt, csr, h2, as2, ad2, b2, out);
}